// Round 1
// baseline (2434.932 us; speedup 1.0000x reference)
//
#include <hip/hip_runtime.h>
#include <hip/hip_bf16.h>

// Problem constants
#define BB 4
#define LL 1024
#define NFE 480
#define HH 32
#define FCC 512
#define DD 512
#define WW 65
#define BL (BB*LL)          // 4096
#define BLH (BL*HH)         // 131072
#define KSZ (WW*DD*HH)      // 1064960

// Static device scratch (avoids any ws_size assumption). ~42 MB.
__device__ float g_oef[BL*FCC];     // concat(x_embeds, cls)
__device__ float g_cf0[BL*DD];
__device__ float g_cf1[BL*DD];
__device__ float g_m[BL];           // masks + x[...,21]+x[...,22]
__device__ float g_k[3*KSZ];        // k0,k1,k2  (w,d,h) h-contiguous
__device__ float g_acts[3*BLH];     // acts0, acts1, acts2
__device__ float g_small[4*BLH];    // g1=cf1@A1, g3=cf0@A3, g4=cf1@A4, pp=oef@pdw
__device__ float g_gt[HH*LL];       // Gaussian distance table per h
__device__ float g_vsum[BLH];       // sum_j gt[h][|i-j|] m[b,j]

// ---------------- K1: softmax + concat + m ----------------
__global__ __launch_bounds__(256) void k1_prep(const float* __restrict__ x_embeds,
                                               const float* __restrict__ latent,
                                               const float* __restrict__ masks,
                                               const float* __restrict__ x) {
    const int tid  = threadIdx.x;
    const int row0 = blockIdx.x * 8;
    const int r    = row0 + (tid >> 5);
    const int lane = tid & 31;

    const float mask = masks[r];
    float v = latent[r*HH + lane] * mask;
    float mx = v;
    #pragma unroll
    for (int off = 16; off > 0; off >>= 1) mx = fmaxf(mx, __shfl_xor(mx, off, 32));
    float e = __expf(v - mx);
    float s = e;
    #pragma unroll
    for (int off = 16; off > 0; off >>= 1) s += __shfl_xor(s, off, 32);
    g_oef[r*FCC + NFE + lane] = e / s * mask;

    if (lane == 0) g_m[r] = mask + x[r*23 + 21] + x[r*23 + 22];

    // copy x_embeds rows into oef[:, :480]
    for (int idx = tid; idx < 8*NFE; idx += 256) {
        int rr = idx / NFE, c = idx - rr*NFE;
        g_oef[(row0+rr)*FCC + c] = x_embeds[(row0+rr)*NFE + c];
    }
}

// ---------------- K2: cf0/cf1 = oef @ knn[z] (fp32 tiled GEMM) ----------------
__global__ __launch_bounds__(256) void k2_gemm(const float* __restrict__ knn) {
    const int t  = threadIdx.x;
    const int tx = t & 15, ty = t >> 4;
    const int m0 = blockIdx.y * 128, n0 = blockIdx.x * 64;
    const float* __restrict__ Bmat = knn + (size_t)blockIdx.z * (FCC*DD);
    float* __restrict__ C = blockIdx.z ? g_cf1 : g_cf0;

    __shared__ float As[16][132];   // [k][m], padded
    __shared__ float Bs[16][64];    // [k][n]

    float acc[8][4];
    #pragma unroll
    for (int i = 0; i < 8; ++i)
        #pragma unroll
        for (int j = 0; j < 4; ++j) acc[i][j] = 0.f;

    for (int k0 = 0; k0 < FCC; k0 += 16) {
        #pragma unroll
        for (int i = 0; i < 2; ++i) {
            int idx4 = t + i*256;
            int row = idx4 >> 2;
            int c4  = (idx4 & 3) * 4;
            float4 a = *reinterpret_cast<const float4*>(&g_oef[(size_t)(m0+row)*FCC + k0 + c4]);
            As[c4+0][row] = a.x; As[c4+1][row] = a.y; As[c4+2][row] = a.z; As[c4+3][row] = a.w;
        }
        {
            int row = t >> 4, c4 = (t & 15) * 4;
            *reinterpret_cast<float4*>(&Bs[row][c4]) =
                *reinterpret_cast<const float4*>(&Bmat[(size_t)(k0+row)*DD + n0 + c4]);
        }
        __syncthreads();
        #pragma unroll
        for (int k = 0; k < 16; ++k) {
            float4 a0 = *reinterpret_cast<const float4*>(&As[k][ty*8]);
            float4 a1 = *reinterpret_cast<const float4*>(&As[k][ty*8+4]);
            float4 b  = *reinterpret_cast<const float4*>(&Bs[k][tx*4]);
            float av[8] = {a0.x,a0.y,a0.z,a0.w,a1.x,a1.y,a1.z,a1.w};
            float bv[4] = {b.x,b.y,b.z,b.w};
            #pragma unroll
            for (int i = 0; i < 8; ++i)
                #pragma unroll
                for (int j = 0; j < 4; ++j)
                    acc[i][j] = fmaf(av[i], bv[j], acc[i][j]);
        }
        __syncthreads();
    }
    #pragma unroll
    for (int i = 0; i < 8; ++i) {
        int row = m0 + ty*8 + i;
        float4 o = make_float4(acc[i][0], acc[i][1], acc[i][2], acc[i][3]);
        *reinterpret_cast<float4*>(&C[(size_t)row*DD + n0 + tx*4]) = o;
    }
}

// ---------------- K3: build k0/k1/k2 ----------------
__global__ __launch_bounds__(256) void k3_kgen(const float* __restrict__ ampl,
                                               const float* __restrict__ inp,
                                               const float* __restrict__ outv,
                                               const float* __restrict__ pos) {
    int idx = blockIdx.x * 256 + threadIdx.x;   // < 3*KSZ exactly
    int v   = idx / KSZ;
    int rem = idx - v*KSZ;
    int w   = rem / (DD*HH);
    int r2  = rem - w*(DD*HH);
    int d   = r2 / HH;
    int h   = r2 - d*HH;

    const float c0 = 0.01f;   // 1/MAX0^2
    float a, mean, iv;
    if (v == 0) {
        a    = ampl[0*DD*HH + d*HH + h];
        mean = inp[0*DD + d] * outv[0*HH + h];
        iv   = fabsf(inp[1*DD + d] * outv[1*HH + h]) + c0;
    } else if (v == 1) {
        a    = ampl[1*DD*HH + d*HH + h];
        mean = 0.f;
        iv   = fabsf(inp[2*DD + d] * outv[2*HH + h]) + c0;
    } else {
        a    = ampl[2*DD*HH + d*HH + h];
        mean = inp[3*DD + d] * outv[3*HH + h];
        iv   = fabsf(inp[4*DD + d] * outv[4*HH + h]) + c0;
    }
    float tt = pos[w] - mean;
    g_k[idx] = __expf(-iv * tt * tt) * a;
}

// ---------------- K3b: Gaussian distance table ----------------
__global__ __launch_bounds__(256) void k3b_gt(const float* __restrict__ bias) {
    int idx = blockIdx.x * 256 + threadIdx.x;   // < HH*LL
    int h = idx / LL;
    int dist = idx - h*LL;
    float cm = bias[4*HH + h];
    float sig = cm*cm + 1e-4f;                  // 1/MAX1^2
    float dd = (float)dist;
    g_gt[idx] = __expf(-sig * dd * dd);
}

// ---------------- K4: 3 fused convs ----------------
__global__ __launch_bounds__(256) void k4_conv() {
    const int act = blockIdx.z;                 // 0,1,2
    const int b   = blockIdx.y;
    const int l   = blockIdx.x * 32 + (threadIdx.x >> 3);
    const int h0  = (threadIdx.x & 7) * 4;
    const float* __restrict__ f  = (act == 1) ? g_cf1 : g_cf0;
    const float* __restrict__ kk = g_k + (size_t)act * KSZ;

    float4 acc = make_float4(0.f, 0.f, 0.f, 0.f);
    for (int w = 0; w < WW; ++w) {
        int ls = l + w - 32;
        if ((unsigned)ls >= LL) continue;
        const float* __restrict__ frow = f + (size_t)(b*LL + ls) * DD;
        const float* __restrict__ krow = kk + (size_t)w * DD*HH + h0;
        #pragma unroll 2
        for (int d = 0; d < DD; d += 4) {
            float4 fv4 = *reinterpret_cast<const float4*>(frow + d);
            float fv[4] = {fv4.x, fv4.y, fv4.z, fv4.w};
            #pragma unroll
            for (int j = 0; j < 4; ++j) {
                float4 kv = *reinterpret_cast<const float4*>(krow + (size_t)(d+j)*HH);
                acc.x = fmaf(fv[j], kv.x, acc.x);
                acc.y = fmaf(fv[j], kv.y, acc.y);
                acc.z = fmaf(fv[j], kv.z, acc.z);
                acc.w = fmaf(fv[j], kv.w, acc.w);
            }
        }
    }
    *reinterpret_cast<float4*>(&g_acts[(size_t)act*BLH + (size_t)(b*LL + l)*HH + h0]) = acc;
}

// ---------------- K5: small GEMMs (N=32, K=512) ----------------
__global__ __launch_bounds__(256) void k5_small(const float* __restrict__ ampl,
                                                const float* __restrict__ pdw) {
    const int o = blockIdx.y;                   // 0..3
    const int r = blockIdx.x * 8 + (threadIdx.x >> 5);
    const int h = threadIdx.x & 31;
    const float* Arow;
    const float* Bm;
    if (o == 0)      { Arow = g_cf1 + (size_t)r*DD;  Bm = ampl + 1*DD*HH; }
    else if (o == 1) { Arow = g_cf0 + (size_t)r*DD;  Bm = ampl + 3*DD*HH; }
    else if (o == 2) { Arow = g_cf1 + (size_t)r*DD;  Bm = ampl + 4*DD*HH; }
    else             { Arow = g_oef + (size_t)r*FCC; Bm = pdw; }

    float acc = 0.f;
    #pragma unroll 4
    for (int k = 0; k < DD; ++k)
        acc = fmaf(Arow[k], Bm[(size_t)k*HH + h], acc);
    g_small[(size_t)o*BLH + (size_t)r*HH + h] = acc;
}

// ---------------- K6: Toeplitz mask correction ----------------
__global__ __launch_bounds__(256) void k6_vc() {
    __shared__ float ml[LL];
    const int b = blockIdx.y;
    for (int j = threadIdx.x; j < LL; j += 256) ml[j] = g_m[b*LL + j];
    __syncthreads();
    const int i = blockIdx.x * 8 + (threadIdx.x & 7);
    const int h = threadIdx.x >> 3;
    const float* __restrict__ gt = g_gt + (size_t)h * LL;
    float acc = 0.f;
    #pragma unroll 4
    for (int j = 0; j < LL; ++j) {
        int dd = i - j; dd = dd < 0 ? -dd : dd;
        acc = fmaf(gt[dd], ml[j], acc);
    }
    g_vsum[(size_t)(b*LL + i)*HH + h] = acc;
}

// ---------------- K7: final combine ----------------
__global__ __launch_bounds__(256) void k7_final(const float* __restrict__ masks,
                                                const float* __restrict__ bias,
                                                float* __restrict__ out) {
    int idx = blockIdx.x * 256 + threadIdx.x;   // < BLH
    int r = idx >> 5, h = idx & 31;
    float a0 = g_acts[idx];
    float a1 = g_acts[BLH + idx];
    float a2 = g_acts[2*BLH + idx];
    float rdf = (a0 + bias[0*HH + h]) * a1
              + a2 * (g_small[idx] + bias[2*HH + h])
              + (g_small[BLH + idx] + bias[1*HH + h]) * g_small[2*BLH + idx];
    float pp = g_small[3*BLH + idx] + bias[3*HH + h];
    float vc = g_m[r] * g_vsum[idx];
    out[idx] = vc * pp * rdf * masks[r];
}

extern "C" void kernel_launch(void* const* d_in, const int* in_sizes, int n_in,
                              void* d_out, int out_size, void* d_ws, size_t ws_size,
                              hipStream_t stream) {
    (void)in_sizes; (void)n_in; (void)d_ws; (void)ws_size; (void)out_size;
    const float* x_embeds = (const float*)d_in[0];
    const float* latent   = (const float*)d_in[1];
    const float* masks    = (const float*)d_in[2];
    const float* pos      = (const float*)d_in[3];
    const float* x        = (const float*)d_in[4];
    const float* ampl     = (const float*)d_in[5];
    const float* inp      = (const float*)d_in[6];
    const float* outv     = (const float*)d_in[7];
    const float* bias     = (const float*)d_in[8];
    const float* pdw      = (const float*)d_in[9];
    const float* knn      = (const float*)d_in[10];
    float* out = (float*)d_out;

    hipLaunchKernelGGL(k1_prep, dim3(BL/8), dim3(256), 0, stream, x_embeds, latent, masks, x);
    hipLaunchKernelGGL(k3_kgen, dim3(3*KSZ/256), dim3(256), 0, stream, ampl, inp, outv, pos);
    hipLaunchKernelGGL(k3b_gt, dim3(HH*LL/256), dim3(256), 0, stream, bias);
    hipLaunchKernelGGL(k2_gemm, dim3(DD/64, BL/128, 2), dim3(256), 0, stream, knn);
    hipLaunchKernelGGL(k4_conv, dim3(LL/32, BB, 3), dim3(256), 0, stream);
    hipLaunchKernelGGL(k5_small, dim3(BL/8, 4), dim3(256), 0, stream, ampl, pdw);
    hipLaunchKernelGGL(k6_vc, dim3(LL/8, BB), dim3(256), 0, stream);
    hipLaunchKernelGGL(k7_final, dim3(BLH/256), dim3(256), 0, stream, masks, bias, out);
}

// Round 3
// 241.134 us; speedup vs baseline: 10.0978x; 10.0978x over previous
//
#include <hip/hip_runtime.h>
#include <hip/hip_bf16.h>

// Problem constants
#define BB 4
#define LL 1024
#define NFE 480
#define HH 32
#define FCC 512
#define DD 512
#define WW 65
#define BL (BB*LL)          // 4096
#define BLH (BL*HH)         // 131072
#define LPAD 1088           // 1024 + 2*32 halo

typedef short bf16x8 __attribute__((ext_vector_type(8)));
typedef float f32x16 __attribute__((ext_vector_type(16)));
typedef unsigned short us8 __attribute__((ext_vector_type(8)));
typedef unsigned short us4 __attribute__((ext_vector_type(4)));

__device__ inline unsigned short f2bf(float x) {
    union { float f; unsigned u; } v; v.f = x;
    unsigned r = v.u + 0x7FFFu + ((v.u >> 16) & 1u);
    return (unsigned short)(r >> 16);
}

// Static device scratch
__device__ float  g_oef[BL*FCC];        // concat(x_embeds, cls) fp32
__device__ float  g_cf0[BL*DD];
__device__ float  g_cf1[BL*DD];
__device__ float  g_m[BL];
__device__ unsigned short g_fpad[2*BB*LPAD*DD];   // bf16 cf0/cf1, zero-padded rows
__device__ unsigned short g_kb2[(size_t)3*WW*4*8*64*8]; // k in B-frag order
__device__ float  g_actsp[8][3*BLH];    // per-(dh,wave) partials: slot = dh*4+wave
__device__ float  g_small[4*BLH];
__device__ float  g_gt[HH*LL];
__device__ float  g_vsum[BLH];

// ---------------- K1: softmax + concat + m ----------------
__global__ __launch_bounds__(256) void k1_prep(const float* __restrict__ x_embeds,
                                               const float* __restrict__ latent,
                                               const float* __restrict__ masks,
                                               const float* __restrict__ x) {
    const int tid  = threadIdx.x;
    const int row0 = blockIdx.x * 8;
    const int r    = row0 + (tid >> 5);
    const int lane = tid & 31;

    const float mask = masks[r];
    float v = latent[r*HH + lane] * mask;
    float mx = v;
    #pragma unroll
    for (int off = 16; off > 0; off >>= 1) mx = fmaxf(mx, __shfl_xor(mx, off, 32));
    float e = __expf(v - mx);
    float s = e;
    #pragma unroll
    for (int off = 16; off > 0; off >>= 1) s += __shfl_xor(s, off, 32);
    g_oef[r*FCC + NFE + lane] = e / s * mask;

    if (lane == 0) g_m[r] = mask + x[r*23 + 21] + x[r*23 + 22];

    for (int idx = tid; idx < 8*NFE; idx += 256) {
        int rr = idx / NFE, c = idx - rr*NFE;
        g_oef[(row0+rr)*FCC + c] = x_embeds[(row0+rr)*NFE + c];
    }
}

// ---------------- K0: zero the halo rows of g_fpad ----------------
__global__ __launch_bounds__(256) void k0_zero() {
    int idx = blockIdx.x * 256 + threadIdx.x;       // < 32768 chunks of 16B
    int fzb = idx >> 12;                            // 0..7  (fz*4+b)
    int rem = idx & 4095;
    int rowi = rem >> 6;                            // 0..63
    int col8 = rem & 63;
    int row = (rowi < 32) ? rowi : (1024 + rowi);   // 0..31 or 1056..1087
    int4 z = make_int4(0,0,0,0);
    *reinterpret_cast<int4*>(&g_fpad[((size_t)fzb*LPAD + row)*DD + col8*8]) = z;
}

// ---------------- K2: cf0/cf1 = oef @ knn[z] (fp32 tiled GEMM) + bf16 dual-write ----------------
__global__ __launch_bounds__(256) void k2_gemm(const float* __restrict__ knn) {
    const int t  = threadIdx.x;
    const int tx = t & 15, ty = t >> 4;
    const int m0 = blockIdx.y * 128, n0 = blockIdx.x * 64;
    const float* __restrict__ Bmat = knn + (size_t)blockIdx.z * (FCC*DD);
    float* __restrict__ C = blockIdx.z ? g_cf1 : g_cf0;

    __shared__ float As[16][132];
    __shared__ float Bs[16][64];

    float acc[8][4];
    #pragma unroll
    for (int i = 0; i < 8; ++i)
        #pragma unroll
        for (int j = 0; j < 4; ++j) acc[i][j] = 0.f;

    for (int k0 = 0; k0 < FCC; k0 += 16) {
        #pragma unroll
        for (int i = 0; i < 2; ++i) {
            int idx4 = t + i*256;
            int row = idx4 >> 2;
            int c4  = (idx4 & 3) * 4;
            float4 a = *reinterpret_cast<const float4*>(&g_oef[(size_t)(m0+row)*FCC + k0 + c4]);
            As[c4+0][row] = a.x; As[c4+1][row] = a.y; As[c4+2][row] = a.z; As[c4+3][row] = a.w;
        }
        {
            int row = t >> 4, c4 = (t & 15) * 4;
            *reinterpret_cast<float4*>(&Bs[row][c4]) =
                *reinterpret_cast<const float4*>(&Bmat[(size_t)(k0+row)*DD + n0 + c4]);
        }
        __syncthreads();
        #pragma unroll
        for (int k = 0; k < 16; ++k) {
            float4 a0 = *reinterpret_cast<const float4*>(&As[k][ty*8]);
            float4 a1 = *reinterpret_cast<const float4*>(&As[k][ty*8+4]);
            float4 b  = *reinterpret_cast<const float4*>(&Bs[k][tx*4]);
            float av[8] = {a0.x,a0.y,a0.z,a0.w,a1.x,a1.y,a1.z,a1.w};
            float bv[4] = {b.x,b.y,b.z,b.w};
            #pragma unroll
            for (int i = 0; i < 8; ++i)
                #pragma unroll
                for (int j = 0; j < 4; ++j)
                    acc[i][j] = fmaf(av[i], bv[j], acc[i][j]);
        }
        __syncthreads();
    }
    #pragma unroll
    for (int i = 0; i < 8; ++i) {
        int r = m0 + ty*8 + i;
        float4 o = make_float4(acc[i][0], acc[i][1], acc[i][2], acc[i][3]);
        *reinterpret_cast<float4*>(&C[(size_t)r*DD + n0 + tx*4]) = o;
        int bb_ = r >> 10, ll_ = r & 1023;
        us4 ub; ub[0]=f2bf(acc[i][0]); ub[1]=f2bf(acc[i][1]); ub[2]=f2bf(acc[i][2]); ub[3]=f2bf(acc[i][3]);
        *reinterpret_cast<us4*>(&g_fpad[((size_t)(blockIdx.z*BB + bb_)*LPAD + 32 + ll_)*DD + n0 + tx*4]) = ub;
    }
}

// ---------------- K3: build k in MFMA B-fragment order ----------------
// layout: [z][w][dt(4)][ks(8)][lane(64)][i(8)]  (bf16)
__global__ __launch_bounds__(256) void k3_kb2(const float* __restrict__ ampl,
                                              const float* __restrict__ inp,
                                              const float* __restrict__ outv,
                                              const float* __restrict__ pos) {
    const int z = blockIdx.z;
    const int w = blockIdx.y;
    const int idx = blockIdx.x * 256 + threadIdx.x;   // 0..2047 within (z,w)
    const int lane = idx & 63;
    const int ks   = (idx >> 6) & 7;
    const int dt   = idx >> 9;
    const int h    = lane & 31;
    const int d8   = dt*128 + ks*16 + (lane >> 5)*8;

    const float c0 = 0.01f;
    const float p = pos[w];
    int ai, mi, vi;
    if (z == 0)      { ai = 0; mi = 0;  vi = 1; }
    else if (z == 1) { ai = 1; mi = -1; vi = 2; }
    else             { ai = 2; mi = 3;  vi = 4; }

    us8 out;
    #pragma unroll
    for (int i = 0; i < 8; ++i) {
        int d = d8 + i;
        float a    = ampl[(size_t)ai*DD*HH + d*HH + h];
        float mean = (mi >= 0) ? inp[mi*DD + d] * outv[mi*HH + h] : 0.f;
        float iv   = fabsf(inp[vi*DD + d] * outv[vi*HH + h]) + c0;
        float tt = p - mean;
        out[i] = f2bf(__expf(-iv * tt * tt) * a);
    }
    *reinterpret_cast<us8*>(&g_kb2[((((size_t)z*WW + w)*4 + dt)*8 + ks)*512 + (size_t)lane*8]) = out;
}

// ---------------- K3b: Gaussian distance table ----------------
__global__ __launch_bounds__(256) void k3b_gt(const float* __restrict__ bias) {
    int idx = blockIdx.x * 256 + threadIdx.x;
    int h = idx / LL;
    int dist = idx - h*LL;
    float cm = bias[4*HH + h];
    float sig = cm*cm + 1e-4f;
    float dd = (float)dist;
    g_gt[idx] = __expf(-sig * dd * dd);
}

// ---------------- K4: MFMA implicit conv-GEMM ----------------
// grid: (ltile=16, b=4, z*2+dhalf=6); block 256 = 4 waves
// wave = one w-quarter; each (dh,wave) writes its OWN partial slot (summed in k7).
__global__ __launch_bounds__(256) void k4_mfma() {
    const int lt = blockIdx.x;
    const int b  = blockIdx.y;
    const int z  = blockIdx.z >> 1;
    const int dh = blockIdx.z & 1;
    const int fz = (z == 1) ? 1 : 0;
    const int t  = threadIdx.x;
    const int wave = t >> 6, lane = t & 63;
    const int l31 = lane & 31, khalf = lane >> 5;

    __shared__ __align__(16) unsigned short smem[128*128];  // 32 KB f tile (swizzled)

    const int wbeg = (wave == 0) ? 0 : 17 + (wave - 1)*16;
    const int wend = (wave == 0) ? 17 : wbeg + 16;

    f32x16 acc0, acc1;
    #pragma unroll
    for (int i = 0; i < 16; ++i) { acc0[i] = 0.f; acc1[i] = 0.f; }

    for (int dti = 0; dti < 2; ++dti) {
        const int dt = dh*2 + dti;
        __syncthreads();
        // stage f tile: rows lt*64 .. +127 (padded space), cols dt*128..+127
        const unsigned short* src =
            g_fpad + ((size_t)(fz*BB + b)*LPAD + lt*64) * DD + dt*128;
        #pragma unroll
        for (int c = 0; c < 8; ++c) {
            int q = c*256 + t;
            int row = q >> 4, slot = q & 15;
            int4 v = *reinterpret_cast<const int4*>(src + (size_t)row*DD + slot*8);
            int off = row*256 + ((slot*16) ^ ((row & 15) << 4));
            *reinterpret_cast<int4*>((char*)smem + off) = v;
        }
        __syncthreads();

        for (int w = wbeg; w < wend; ++w) {
            const unsigned short* kbw =
                g_kb2 + ((((size_t)z*WW + w)*4 + dt)*8)*512;
            const int r0 = l31 + w;
            const int r1 = r0 + 32;
            #pragma unroll
            for (int ks = 0; ks < 8; ++ks) {
                bf16x8 bf = *reinterpret_cast<const bf16x8*>(kbw + ks*512 + lane*8);
                int dby = ks*32 + khalf*16;
                bf16x8 a0 = *reinterpret_cast<const bf16x8*>(
                    (char*)smem + r0*256 + (dby ^ ((r0 & 15) << 4)));
                bf16x8 a1 = *reinterpret_cast<const bf16x8*>(
                    (char*)smem + r1*256 + (dby ^ ((r1 & 15) << 4)));
                acc0 = __builtin_amdgcn_mfma_f32_32x32x16_bf16(a0, bf, acc0, 0, 0, 0);
                acc1 = __builtin_amdgcn_mfma_f32_32x32x16_bf16(a1, bf, acc1, 0, 0, 0);
            }
        }
    }

    // epilogue: D col = lane&31 (=h), row = (reg&3) + 8*(reg>>2) + 4*(lane>>5)
    // Each (dh,wave) writes its own partial slot; k7 sums the 8 slots.
    float* outp = g_actsp[dh*4 + wave] + (size_t)z*BLH + ((size_t)b*LL + lt*64)*HH;
    #pragma unroll
    for (int reg = 0; reg < 16; ++reg) {
        int row = (reg & 3) + 8*(reg >> 2) + 4*khalf;
        outp[(size_t)row*HH + l31]        = acc0[reg];
        outp[(size_t)(32 + row)*HH + l31] = acc1[reg];
    }
}

// ---------------- K5: small GEMMs (N=32, K=512) ----------------
__global__ __launch_bounds__(256) void k5_small(const float* __restrict__ ampl,
                                                const float* __restrict__ pdw) {
    const int o = blockIdx.y;
    const int r = blockIdx.x * 8 + (threadIdx.x >> 5);
    const int h = threadIdx.x & 31;
    const float* Arow;
    const float* Bm;
    if (o == 0)      { Arow = g_cf1 + (size_t)r*DD;  Bm = ampl + 1*DD*HH; }
    else if (o == 1) { Arow = g_cf0 + (size_t)r*DD;  Bm = ampl + 3*DD*HH; }
    else if (o == 2) { Arow = g_cf1 + (size_t)r*DD;  Bm = ampl + 4*DD*HH; }
    else             { Arow = g_oef + (size_t)r*FCC; Bm = pdw; }

    float acc = 0.f;
    #pragma unroll 4
    for (int k = 0; k < DD; ++k)
        acc = fmaf(Arow[k], Bm[(size_t)k*HH + h], acc);
    g_small[(size_t)o*BLH + (size_t)r*HH + h] = acc;
}

// ---------------- K6: Toeplitz mask correction ----------------
__global__ __launch_bounds__(256) void k6_vc() {
    __shared__ float ml[LL];
    const int b = blockIdx.y;
    for (int j = threadIdx.x; j < LL; j += 256) ml[j] = g_m[b*LL + j];
    __syncthreads();
    const int i = blockIdx.x * 8 + (threadIdx.x & 7);
    const int h = threadIdx.x >> 3;
    const float* __restrict__ gt = g_gt + (size_t)h * LL;
    float acc = 0.f;
    #pragma unroll 4
    for (int j = 0; j < LL; ++j) {
        int dd = i - j; dd = dd < 0 ? -dd : dd;
        acc = fmaf(gt[dd], ml[j], acc);
    }
    g_vsum[(size_t)(b*LL + i)*HH + h] = acc;
}

// ---------------- K7: final combine (sums the 8 conv partial slots) ----------------
__global__ __launch_bounds__(256) void k7_final(const float* __restrict__ masks,
                                                const float* __restrict__ bias,
                                                float* __restrict__ out) {
    int idx = blockIdx.x * 256 + threadIdx.x;
    int r = idx >> 5, h = idx & 31;
    float a0 = 0.f, a1 = 0.f, a2 = 0.f;
    #pragma unroll
    for (int s = 0; s < 8; ++s) {
        a0 += g_actsp[s][idx];
        a1 += g_actsp[s][BLH + idx];
        a2 += g_actsp[s][2*BLH + idx];
    }
    float rdf = (a0 + bias[0*HH + h]) * a1
              + a2 * (g_small[idx] + bias[2*HH + h])
              + (g_small[BLH + idx] + bias[1*HH + h]) * g_small[2*BLH + idx];
    float pp = g_small[3*BLH + idx] + bias[3*HH + h];
    float vc = g_m[r] * g_vsum[idx];
    out[idx] = vc * pp * rdf * masks[r];
}

extern "C" void kernel_launch(void* const* d_in, const int* in_sizes, int n_in,
                              void* d_out, int out_size, void* d_ws, size_t ws_size,
                              hipStream_t stream) {
    (void)in_sizes; (void)n_in; (void)d_ws; (void)ws_size; (void)out_size;
    const float* x_embeds = (const float*)d_in[0];
    const float* latent   = (const float*)d_in[1];
    const float* masks    = (const float*)d_in[2];
    const float* pos      = (const float*)d_in[3];
    const float* x        = (const float*)d_in[4];
    const float* ampl     = (const float*)d_in[5];
    const float* inp      = (const float*)d_in[6];
    const float* outv     = (const float*)d_in[7];
    const float* bias     = (const float*)d_in[8];
    const float* pdw      = (const float*)d_in[9];
    const float* knn      = (const float*)d_in[10];
    float* out = (float*)d_out;

    hipLaunchKernelGGL(k1_prep, dim3(BL/8), dim3(256), 0, stream, x_embeds, latent, masks, x);
    hipLaunchKernelGGL(k0_zero, dim3(128), dim3(256), 0, stream);
    hipLaunchKernelGGL(k3_kb2, dim3(8, WW, 3), dim3(256), 0, stream, ampl, inp, outv, pos);
    hipLaunchKernelGGL(k3b_gt, dim3(HH*LL/256), dim3(256), 0, stream, bias);
    hipLaunchKernelGGL(k2_gemm, dim3(DD/64, BL/128, 2), dim3(256), 0, stream, knn);
    hipLaunchKernelGGL(k4_mfma, dim3(16, BB, 6), dim3(256), 0, stream);
    hipLaunchKernelGGL(k5_small, dim3(BL/8, 4), dim3(256), 0, stream, ampl, pdw);
    hipLaunchKernelGGL(k6_vc, dim3(LL/8, BB), dim3(256), 0, stream);
    hipLaunchKernelGGL(k7_final, dim3(BLH/256), dim3(256), 0, stream, masks, bias, out);
}

// Round 4
// 199.740 us; speedup vs baseline: 12.1905x; 1.2072x over previous
//
#include <hip/hip_runtime.h>
#include <hip/hip_bf16.h>

// Problem constants
#define BB 4
#define LL 1024
#define NFE 480
#define HH 32
#define FCC 512
#define DD 512
#define WW 65
#define BL (BB*LL)          // 4096
#define BLH (BL*HH)         // 131072
#define LPAD 1088           // 1024 + 2*32 halo

typedef short bf16x8 __attribute__((ext_vector_type(8)));
typedef float f32x16 __attribute__((ext_vector_type(16)));
typedef unsigned short us8 __attribute__((ext_vector_type(8)));
typedef unsigned short us4 __attribute__((ext_vector_type(4)));

__device__ inline unsigned short f2bf(float x) {
    union { float f; unsigned u; } v; v.f = x;
    unsigned r = v.u + 0x7FFFu + ((v.u >> 16) & 1u);
    return (unsigned short)(r >> 16);
}
__device__ inline float bf2f(unsigned short u) {
    union { unsigned u; float f; } v; v.u = ((unsigned)u) << 16;
    return v.f;
}

// Static device scratch
__device__ __align__(16) unsigned short g_oefb[BL*FCC];   // bf16 concat(x_embeds, cls)
__device__ __align__(16) unsigned short g_knt[2*DD*FCC];  // bf16 knn^T [z][n][k]
__device__ float  g_m[BL];
__device__ __align__(16) unsigned short g_fpad[2*BB*LPAD*DD];   // bf16 cf0/cf1, zero-padded rows
__device__ __align__(16) unsigned short g_kb2[(size_t)3*WW*4*8*64*8]; // k in B-frag order
__device__ float  g_actsp[8][3*BLH];    // per-(dh,wave) partials: slot = dh*4+wave
__device__ float  g_small[4*BLH];
__device__ float  g_gt[HH*LL];
__device__ float  g_vsum[BLH];

// ---------------- K1: softmax + concat (bf16) + m ----------------
__global__ __launch_bounds__(256) void k1_prep(const float* __restrict__ x_embeds,
                                               const float* __restrict__ latent,
                                               const float* __restrict__ masks,
                                               const float* __restrict__ x) {
    const int tid  = threadIdx.x;
    const int row0 = blockIdx.x * 8;
    const int r    = row0 + (tid >> 5);
    const int lane = tid & 31;

    const float mask = masks[r];
    float v = latent[r*HH + lane] * mask;
    float mx = v;
    #pragma unroll
    for (int off = 16; off > 0; off >>= 1) mx = fmaxf(mx, __shfl_xor(mx, off, 32));
    float e = __expf(v - mx);
    float s = e;
    #pragma unroll
    for (int off = 16; off > 0; off >>= 1) s += __shfl_xor(s, off, 32);
    g_oefb[r*FCC + NFE + lane] = f2bf(e / s * mask);

    if (lane == 0) g_m[r] = mask + x[r*23 + 21] + x[r*23 + 22];

    for (int idx = tid; idx < 8*NFE; idx += 256) {
        int rr = idx / NFE, c = idx - rr*NFE;
        g_oefb[(row0+rr)*FCC + c] = f2bf(x_embeds[(row0+rr)*NFE + c]);
    }
}

// ---------------- K0: zero the halo rows of g_fpad ----------------
__global__ __launch_bounds__(256) void k0_zero() {
    int idx = blockIdx.x * 256 + threadIdx.x;       // < 32768 chunks of 16B
    int fzb = idx >> 12;                            // 0..7  (fz*4+b)
    int rem = idx & 4095;
    int rowi = rem >> 6;                            // 0..63
    int col8 = rem & 63;
    int row = (rowi < 32) ? rowi : (1024 + rowi);   // 0..31 or 1056..1087
    int4 z = make_int4(0,0,0,0);
    *reinterpret_cast<int4*>(&g_fpad[((size_t)fzb*LPAD + row)*DD + col8*8]) = z;
}

// ---------------- K3c: knn -> bf16 transpose g_knt[z][n][k] ----------------
__global__ __launch_bounds__(256) void k3c_knt(const float* __restrict__ knn) {
    __shared__ unsigned short tile[64][65];
    const int z  = blockIdx.z;
    const int k0 = blockIdx.x * 64;
    const int n0 = blockIdx.y * 64;
    const float* __restrict__ src = knn + (size_t)z*FCC*DD;
    #pragma unroll 4
    for (int i = 0; i < 16; ++i) {
        int idx = i*256 + threadIdx.x;
        int kk = idx >> 6, nn = idx & 63;
        tile[kk][nn] = f2bf(src[(size_t)(k0+kk)*DD + n0+nn]);
    }
    __syncthreads();
    #pragma unroll 4
    for (int i = 0; i < 16; ++i) {
        int idx = i*256 + threadIdx.x;
        int nn = idx >> 6, kk = idx & 63;
        g_knt[((size_t)z*DD + n0+nn)*FCC + k0+kk] = tile[kk][nn];
    }
}

// ---------------- K2: cf0/cf1 via MFMA, bf16 in/out ----------------
// grid (nt=4, mt=32, z=2); block 256 = 4 waves; wave = n-quadrant (32 cols)
// each wave: 4 m-subtiles of 32 rows; K=512 in 4 LDS-staged chunks of 128.
__global__ __launch_bounds__(256) void k2_mfma() {
    const int nt = blockIdx.x;
    const int mt = blockIdx.y;
    const int z  = blockIdx.z;
    const int t  = threadIdx.x;
    const int wave = t >> 6, lane = t & 63;
    const int l31 = lane & 31, khalf = lane >> 5;
    const int n0 = nt*128 + wave*32;
    const int m_base = mt*128;

    __shared__ __align__(16) unsigned short smem[128*128];  // 32 KB A tile (swizzled)

    f32x16 acc[4];
    #pragma unroll
    for (int mti = 0; mti < 4; ++mti)
        #pragma unroll
        for (int i = 0; i < 16; ++i) acc[mti][i] = 0.f;

    const unsigned short* __restrict__ bptr =
        g_knt + ((size_t)z*DD + n0 + l31)*FCC + khalf*8;

    for (int kc = 0; kc < 4; ++kc) {
        __syncthreads();
        const unsigned short* __restrict__ src = g_oefb + (size_t)m_base*FCC + kc*128;
        #pragma unroll
        for (int c = 0; c < 8; ++c) {
            int q = c*256 + t;
            int row = q >> 4, slot = q & 15;
            int4 v = *reinterpret_cast<const int4*>(src + (size_t)row*FCC + slot*8);
            int off = row*256 + ((slot*16) ^ ((row & 15) << 4));
            *reinterpret_cast<int4*>((char*)smem + off) = v;
        }
        __syncthreads();
        #pragma unroll
        for (int ks = 0; ks < 8; ++ks) {
            bf16x8 bf = *reinterpret_cast<const bf16x8*>(bptr + kc*128 + ks*16);
            int dby = ks*32 + khalf*16;
            #pragma unroll
            for (int mti = 0; mti < 4; ++mti) {
                int r = mti*32 + l31;
                bf16x8 a = *reinterpret_cast<const bf16x8*>(
                    (char*)smem + r*256 + (dby ^ ((r & 15) << 4)));
                acc[mti] = __builtin_amdgcn_mfma_f32_32x32x16_bf16(a, bf, acc[mti], 0, 0, 0);
            }
        }
    }

    // epilogue: D col = lane&31 (=n), row = (reg&3)+8*(reg>>2)+4*khalf
    #pragma unroll
    for (int mti = 0; mti < 4; ++mti) {
        #pragma unroll
        for (int reg = 0; reg < 16; ++reg) {
            int rowf = (reg & 3) + 8*(reg >> 2) + 4*khalf;
            int m = m_base + mti*32 + rowf;
            int b_ = m >> 10, l_ = m & 1023;
            g_fpad[((size_t)(z*BB + b_)*LPAD + 32 + l_)*DD + n0 + l31] = f2bf(acc[mti][reg]);
        }
    }
}

// ---------------- K3: build k in MFMA B-fragment order ----------------
// layout: [z][w][dt(4)][ks(8)][lane(64)][i(8)]  (bf16)
__global__ __launch_bounds__(256) void k3_kb2(const float* __restrict__ ampl,
                                              const float* __restrict__ inp,
                                              const float* __restrict__ outv,
                                              const float* __restrict__ pos) {
    const int z = blockIdx.z;
    const int w = blockIdx.y;
    const int idx = blockIdx.x * 256 + threadIdx.x;   // 0..2047 within (z,w)
    const int lane = idx & 63;
    const int ks   = (idx >> 6) & 7;
    const int dt   = idx >> 9;
    const int h    = lane & 31;
    const int d8   = dt*128 + ks*16 + (lane >> 5)*8;

    const float c0 = 0.01f;
    const float p = pos[w];
    int ai, mi, vi;
    if (z == 0)      { ai = 0; mi = 0;  vi = 1; }
    else if (z == 1) { ai = 1; mi = -1; vi = 2; }
    else             { ai = 2; mi = 3;  vi = 4; }

    us8 out;
    #pragma unroll
    for (int i = 0; i < 8; ++i) {
        int d = d8 + i;
        float a    = ampl[(size_t)ai*DD*HH + d*HH + h];
        float mean = (mi >= 0) ? inp[mi*DD + d] * outv[mi*HH + h] : 0.f;
        float iv   = fabsf(inp[vi*DD + d] * outv[vi*HH + h]) + c0;
        float tt = p - mean;
        out[i] = f2bf(__expf(-iv * tt * tt) * a);
    }
    *reinterpret_cast<us8*>(&g_kb2[((((size_t)z*WW + w)*4 + dt)*8 + ks)*512 + (size_t)lane*8]) = out;
}

// ---------------- K3b: Gaussian distance table ----------------
__global__ __launch_bounds__(256) void k3b_gt(const float* __restrict__ bias) {
    int idx = blockIdx.x * 256 + threadIdx.x;
    int h = idx / LL;
    int dist = idx - h*LL;
    float cm = bias[4*HH + h];
    float sig = cm*cm + 1e-4f;
    float dd = (float)dist;
    g_gt[idx] = __expf(-sig * dd * dd);
}

// ---------------- K4: MFMA implicit conv-GEMM ----------------
// grid: (ltile=16, b=4, z*2+dhalf=6); block 256 = 4 waves
// wave = one w-quarter; each (dh,wave) writes its OWN partial slot (summed in k7).
__global__ __launch_bounds__(256) void k4_mfma() {
    const int lt = blockIdx.x;
    const int b  = blockIdx.y;
    const int z  = blockIdx.z >> 1;
    const int dh = blockIdx.z & 1;
    const int fz = (z == 1) ? 1 : 0;
    const int t  = threadIdx.x;
    const int wave = t >> 6, lane = t & 63;
    const int l31 = lane & 31, khalf = lane >> 5;

    __shared__ __align__(16) unsigned short smem[128*128];  // 32 KB f tile (swizzled)

    const int wbeg = (wave == 0) ? 0 : 17 + (wave - 1)*16;
    const int wend = (wave == 0) ? 17 : wbeg + 16;

    f32x16 acc0, acc1;
    #pragma unroll
    for (int i = 0; i < 16; ++i) { acc0[i] = 0.f; acc1[i] = 0.f; }

    for (int dti = 0; dti < 2; ++dti) {
        const int dt = dh*2 + dti;
        __syncthreads();
        const unsigned short* src =
            g_fpad + ((size_t)(fz*BB + b)*LPAD + lt*64) * DD + dt*128;
        #pragma unroll
        for (int c = 0; c < 8; ++c) {
            int q = c*256 + t;
            int row = q >> 4, slot = q & 15;
            int4 v = *reinterpret_cast<const int4*>(src + (size_t)row*DD + slot*8);
            int off = row*256 + ((slot*16) ^ ((row & 15) << 4));
            *reinterpret_cast<int4*>((char*)smem + off) = v;
        }
        __syncthreads();

        for (int w = wbeg; w < wend; ++w) {
            const unsigned short* kbw =
                g_kb2 + ((((size_t)z*WW + w)*4 + dt)*8)*512;
            const int r0 = l31 + w;
            const int r1 = r0 + 32;
            #pragma unroll
            for (int ks = 0; ks < 8; ++ks) {
                bf16x8 bf = *reinterpret_cast<const bf16x8*>(kbw + ks*512 + lane*8);
                int dby = ks*32 + khalf*16;
                bf16x8 a0 = *reinterpret_cast<const bf16x8*>(
                    (char*)smem + r0*256 + (dby ^ ((r0 & 15) << 4)));
                bf16x8 a1 = *reinterpret_cast<const bf16x8*>(
                    (char*)smem + r1*256 + (dby ^ ((r1 & 15) << 4)));
                acc0 = __builtin_amdgcn_mfma_f32_32x32x16_bf16(a0, bf, acc0, 0, 0, 0);
                acc1 = __builtin_amdgcn_mfma_f32_32x32x16_bf16(a1, bf, acc1, 0, 0, 0);
            }
        }
    }

    float* outp = g_actsp[dh*4 + wave] + (size_t)z*BLH + ((size_t)b*LL + lt*64)*HH;
    #pragma unroll
    for (int reg = 0; reg < 16; ++reg) {
        int row = (reg & 3) + 8*(reg >> 2) + 4*khalf;
        outp[(size_t)row*HH + l31]        = acc0[reg];
        outp[(size_t)(32 + row)*HH + l31] = acc1[reg];
    }
}

// ---------------- K5: small GEMMs (N=32, K=512), bf16 A ----------------
__global__ __launch_bounds__(256) void k5_small(const float* __restrict__ ampl,
                                                const float* __restrict__ pdw) {
    const int o = blockIdx.y;
    const int r = blockIdx.x * 8 + (threadIdx.x >> 5);
    const int h = threadIdx.x & 31;
    const int b_ = r >> 10, l_ = r & 1023;
    const unsigned short* Arow;
    const float* Bm;
    if (o == 0)      { Arow = g_fpad + ((size_t)(1*BB + b_)*LPAD + 32 + l_)*DD; Bm = ampl + 1*DD*HH; }
    else if (o == 1) { Arow = g_fpad + ((size_t)(0*BB + b_)*LPAD + 32 + l_)*DD; Bm = ampl + 3*DD*HH; }
    else if (o == 2) { Arow = g_fpad + ((size_t)(1*BB + b_)*LPAD + 32 + l_)*DD; Bm = ampl + 4*DD*HH; }
    else             { Arow = g_oefb + (size_t)r*FCC;                           Bm = pdw; }

    float acc = 0.f;
    #pragma unroll 4
    for (int k = 0; k < DD; ++k)
        acc = fmaf(bf2f(Arow[k]), Bm[(size_t)k*HH + h], acc);
    g_small[(size_t)o*BLH + (size_t)r*HH + h] = acc;
}

// ---------------- K6: Toeplitz mask correction ----------------
__global__ __launch_bounds__(256) void k6_vc() {
    __shared__ float ml[LL];
    const int b = blockIdx.y;
    for (int j = threadIdx.x; j < LL; j += 256) ml[j] = g_m[b*LL + j];
    __syncthreads();
    const int i = blockIdx.x * 8 + (threadIdx.x & 7);
    const int h = threadIdx.x >> 3;
    const float* __restrict__ gt = g_gt + (size_t)h * LL;
    float acc = 0.f;
    #pragma unroll 4
    for (int j = 0; j < LL; ++j) {
        int dd = i - j; dd = dd < 0 ? -dd : dd;
        acc = fmaf(gt[dd], ml[j], acc);
    }
    g_vsum[(size_t)(b*LL + i)*HH + h] = acc;
}

// ---------------- K7: final combine (sums the 8 conv partial slots) ----------------
__global__ __launch_bounds__(256) void k7_final(const float* __restrict__ masks,
                                                const float* __restrict__ bias,
                                                float* __restrict__ out) {
    int idx = blockIdx.x * 256 + threadIdx.x;
    int r = idx >> 5, h = idx & 31;
    float a0 = 0.f, a1 = 0.f, a2 = 0.f;
    #pragma unroll
    for (int s = 0; s < 8; ++s) {
        a0 += g_actsp[s][idx];
        a1 += g_actsp[s][BLH + idx];
        a2 += g_actsp[s][2*BLH + idx];
    }
    float rdf = (a0 + bias[0*HH + h]) * a1
              + a2 * (g_small[idx] + bias[2*HH + h])
              + (g_small[BLH + idx] + bias[1*HH + h]) * g_small[2*BLH + idx];
    float pp = g_small[3*BLH + idx] + bias[3*HH + h];
    float vc = g_m[r] * g_vsum[idx];
    out[idx] = vc * pp * rdf * masks[r];
}

extern "C" void kernel_launch(void* const* d_in, const int* in_sizes, int n_in,
                              void* d_out, int out_size, void* d_ws, size_t ws_size,
                              hipStream_t stream) {
    (void)in_sizes; (void)n_in; (void)d_ws; (void)ws_size; (void)out_size;
    const float* x_embeds = (const float*)d_in[0];
    const float* latent   = (const float*)d_in[1];
    const float* masks    = (const float*)d_in[2];
    const float* pos      = (const float*)d_in[3];
    const float* x        = (const float*)d_in[4];
    const float* ampl     = (const float*)d_in[5];
    const float* inp      = (const float*)d_in[6];
    const float* outv     = (const float*)d_in[7];
    const float* bias     = (const float*)d_in[8];
    const float* pdw      = (const float*)d_in[9];
    const float* knn      = (const float*)d_in[10];
    float* out = (float*)d_out;

    hipLaunchKernelGGL(k1_prep, dim3(BL/8), dim3(256), 0, stream, x_embeds, latent, masks, x);
    hipLaunchKernelGGL(k0_zero, dim3(128), dim3(256), 0, stream);
    hipLaunchKernelGGL(k3c_knt, dim3(8, 8, 2), dim3(256), 0, stream, knn);
    hipLaunchKernelGGL(k3_kb2, dim3(8, WW, 3), dim3(256), 0, stream, ampl, inp, outv, pos);
    hipLaunchKernelGGL(k3b_gt, dim3(HH*LL/256), dim3(256), 0, stream, bias);
    hipLaunchKernelGGL(k2_mfma, dim3(4, 32, 2), dim3(256), 0, stream);
    hipLaunchKernelGGL(k4_mfma, dim3(16, BB, 6), dim3(256), 0, stream);
    hipLaunchKernelGGL(k5_small, dim3(BL/8, 4), dim3(256), 0, stream, ampl, pdw);
    hipLaunchKernelGGL(k6_vc, dim3(LL/8, BB), dim3(256), 0, stream);
    hipLaunchKernelGGL(k7_final, dim3(BLH/256), dim3(256), 0, stream, masks, bias, out);
}

// Round 5
// 149.122 us; speedup vs baseline: 16.3284x; 1.3394x over previous
//
#include <hip/hip_runtime.h>
#include <hip/hip_bf16.h>

// Problem constants
#define BB 4
#define LL 1024
#define NFE 480
#define HH 32
#define FCC 512
#define DD 512
#define WW 65
#define BL (BB*LL)          // 4096
#define BLH (BL*HH)         // 131072
#define LPAD 1088           // 1024 + 2*32 halo

typedef short bf16x8 __attribute__((ext_vector_type(8)));
typedef float f32x16 __attribute__((ext_vector_type(16)));
typedef unsigned short us8 __attribute__((ext_vector_type(8)));
typedef unsigned short us4 __attribute__((ext_vector_type(4)));

__device__ inline unsigned short f2bf(float x) {
    union { float f; unsigned u; } v; v.f = x;
    unsigned r = v.u + 0x7FFFu + ((v.u >> 16) & 1u);
    return (unsigned short)(r >> 16);
}
__device__ inline float bf2f(unsigned short u) {
    union { unsigned u; float f; } v; v.u = ((unsigned)u) << 16;
    return v.f;
}

// Static device scratch
__device__ __align__(16) unsigned short g_oefb[BL*FCC];   // bf16 concat(x_embeds, cls)
__device__ __align__(16) unsigned short g_knt[2*DD*FCC];  // bf16 knn^T [z][n][k]
__device__ float  g_m[BL];
__device__ __align__(16) unsigned short g_fpad[2*BB*LPAD*DD];   // bf16 cf0/cf1, zero-padded rows
__device__ __align__(16) unsigned short g_kb2[(size_t)3*WW*4*8*64*8]; // conv k in B-frag order
__device__ __align__(16) unsigned short g_kbs[4*4*8*64*8];      // small-GEMM B in frag order
__device__ float  g_actsp[8][3*BLH];    // per-(dh,wave) partials: slot = dh*4+wave
__device__ float  g_small[4*BLH];
__device__ float  g_gt[HH*LL];
__device__ float  g_vsum[BLH];

// ---------------- K1: softmax + concat (bf16) + m ----------------
__global__ __launch_bounds__(256) void k1_prep(const float* __restrict__ x_embeds,
                                               const float* __restrict__ latent,
                                               const float* __restrict__ masks,
                                               const float* __restrict__ x) {
    const int tid  = threadIdx.x;
    const int row0 = blockIdx.x * 8;
    const int r    = row0 + (tid >> 5);
    const int lane = tid & 31;

    const float mask = masks[r];
    float v = latent[r*HH + lane] * mask;
    float mx = v;
    #pragma unroll
    for (int off = 16; off > 0; off >>= 1) mx = fmaxf(mx, __shfl_xor(mx, off, 32));
    float e = __expf(v - mx);
    float s = e;
    #pragma unroll
    for (int off = 16; off > 0; off >>= 1) s += __shfl_xor(s, off, 32);
    g_oefb[r*FCC + NFE + lane] = f2bf(e / s * mask);

    if (lane == 0) g_m[r] = mask + x[r*23 + 21] + x[r*23 + 22];

    for (int idx = tid; idx < 8*NFE; idx += 256) {
        int rr = idx / NFE, c = idx - rr*NFE;
        g_oefb[(row0+rr)*FCC + c] = f2bf(x_embeds[(row0+rr)*NFE + c]);
    }
}

// ---------------- K0: zero the halo rows of g_fpad ----------------
__global__ __launch_bounds__(256) void k0_zero() {
    int idx = blockIdx.x * 256 + threadIdx.x;       // < 32768 chunks of 16B
    int fzb = idx >> 12;                            // 0..7  (fz*4+b)
    int rem = idx & 4095;
    int rowi = rem >> 6;                            // 0..63
    int col8 = rem & 63;
    int row = (rowi < 32) ? rowi : (1024 + rowi);   // 0..31 or 1056..1087
    int4 z = make_int4(0,0,0,0);
    *reinterpret_cast<int4*>(&g_fpad[((size_t)fzb*LPAD + row)*DD + col8*8]) = z;
}

// ---------------- K3c: knn -> bf16 transpose g_knt[z][n][k] ----------------
__global__ __launch_bounds__(256) void k3c_knt(const float* __restrict__ knn) {
    __shared__ unsigned short tile[64][65];
    const int z  = blockIdx.z;
    const int k0 = blockIdx.x * 64;
    const int n0 = blockIdx.y * 64;
    const float* __restrict__ src = knn + (size_t)z*FCC*DD;
    #pragma unroll 4
    for (int i = 0; i < 16; ++i) {
        int idx = i*256 + threadIdx.x;
        int kk = idx >> 6, nn = idx & 63;
        tile[kk][nn] = f2bf(src[(size_t)(k0+kk)*DD + n0+nn]);
    }
    __syncthreads();
    #pragma unroll 4
    for (int i = 0; i < 16; ++i) {
        int idx = i*256 + threadIdx.x;
        int nn = idx >> 6, kk = idx & 63;
        g_knt[((size_t)z*DD + n0+nn)*FCC + k0+kk] = tile[kk][nn];
    }
}

// ---------------- K3d: small-GEMM B matrices -> frag order [o][dt][ks][lane][8] ----------------
__global__ __launch_bounds__(256) void k3d_kbs(const float* __restrict__ ampl,
                                               const float* __restrict__ pdw) {
    int t = blockIdx.x*256 + threadIdx.x;   // 0..8191
    int lane = t & 63;
    int ks = (t >> 6) & 7;
    int dt = (t >> 9) & 3;
    int o  = t >> 11;
    int l31 = lane & 31, khalf = lane >> 5;
    const float* S = (o == 0) ? ampl + 1*DD*HH :
                     (o == 1) ? ampl + 3*DD*HH :
                     (o == 2) ? ampl + 4*DD*HH : pdw;
    int k0 = dt*128 + ks*16 + khalf*8;
    us8 out;
    #pragma unroll
    for (int i = 0; i < 8; ++i) out[i] = f2bf(S[(size_t)(k0+i)*HH + l31]);
    *reinterpret_cast<us8*>(&g_kbs[(size_t)t*8]) = out;
}

// ---------------- K2: cf0/cf1 via MFMA, bf16 in/out ----------------
// grid (nt=4, mt=32, z=2); block 256 = 4 waves; wave = n-quadrant (32 cols)
__global__ __launch_bounds__(256) void k2_mfma() {
    const int nt = blockIdx.x;
    const int mt = blockIdx.y;
    const int z  = blockIdx.z;
    const int t  = threadIdx.x;
    const int wave = t >> 6, lane = t & 63;
    const int l31 = lane & 31, khalf = lane >> 5;
    const int n0 = nt*128 + wave*32;
    const int m_base = mt*128;

    __shared__ __align__(16) unsigned short smem[128*128];  // 32 KB A tile (swizzled)

    f32x16 acc[4];
    #pragma unroll
    for (int mti = 0; mti < 4; ++mti)
        #pragma unroll
        for (int i = 0; i < 16; ++i) acc[mti][i] = 0.f;

    const unsigned short* __restrict__ bptr =
        g_knt + ((size_t)z*DD + n0 + l31)*FCC + khalf*8;

    for (int kc = 0; kc < 4; ++kc) {
        __syncthreads();
        const unsigned short* __restrict__ src = g_oefb + (size_t)m_base*FCC + kc*128;
        #pragma unroll
        for (int c = 0; c < 8; ++c) {
            int q = c*256 + t;
            int row = q >> 4, slot = q & 15;
            int4 v = *reinterpret_cast<const int4*>(src + (size_t)row*FCC + slot*8);
            int off = row*256 + ((slot*16) ^ ((row & 15) << 4));
            *reinterpret_cast<int4*>((char*)smem + off) = v;
        }
        __syncthreads();
        #pragma unroll
        for (int ks = 0; ks < 8; ++ks) {
            bf16x8 bf = *reinterpret_cast<const bf16x8*>(bptr + kc*128 + ks*16);
            int dby = ks*32 + khalf*16;
            #pragma unroll
            for (int mti = 0; mti < 4; ++mti) {
                int r = mti*32 + l31;
                bf16x8 a = *reinterpret_cast<const bf16x8*>(
                    (char*)smem + r*256 + (dby ^ ((r & 15) << 4)));
                acc[mti] = __builtin_amdgcn_mfma_f32_32x32x16_bf16(a, bf, acc[mti], 0, 0, 0);
            }
        }
    }

    #pragma unroll
    for (int mti = 0; mti < 4; ++mti) {
        #pragma unroll
        for (int reg = 0; reg < 16; ++reg) {
            int rowf = (reg & 3) + 8*(reg >> 2) + 4*khalf;
            int m = m_base + mti*32 + rowf;
            int b_ = m >> 10, l_ = m & 1023;
            g_fpad[((size_t)(z*BB + b_)*LPAD + 32 + l_)*DD + n0 + l31] = f2bf(acc[mti][reg]);
        }
    }
}

// ---------------- K3: build conv k in MFMA B-frag order ----------------
__global__ __launch_bounds__(256) void k3_kb2(const float* __restrict__ ampl,
                                              const float* __restrict__ inp,
                                              const float* __restrict__ outv,
                                              const float* __restrict__ pos) {
    const int z = blockIdx.z;
    const int w = blockIdx.y;
    const int idx = blockIdx.x * 256 + threadIdx.x;   // 0..2047 within (z,w)
    const int lane = idx & 63;
    const int ks   = (idx >> 6) & 7;
    const int dt   = idx >> 9;
    const int h    = lane & 31;
    const int d8   = dt*128 + ks*16 + (lane >> 5)*8;

    const float c0 = 0.01f;
    const float p = pos[w];
    int ai, mi, vi;
    if (z == 0)      { ai = 0; mi = 0;  vi = 1; }
    else if (z == 1) { ai = 1; mi = -1; vi = 2; }
    else             { ai = 2; mi = 3;  vi = 4; }

    us8 out;
    #pragma unroll
    for (int i = 0; i < 8; ++i) {
        int d = d8 + i;
        float a    = ampl[(size_t)ai*DD*HH + d*HH + h];
        float mean = (mi >= 0) ? inp[mi*DD + d] * outv[mi*HH + h] : 0.f;
        float iv   = fabsf(inp[vi*DD + d] * outv[vi*HH + h]) + c0;
        float tt = p - mean;
        out[i] = f2bf(__expf(-iv * tt * tt) * a);
    }
    *reinterpret_cast<us8*>(&g_kb2[((((size_t)z*WW + w)*4 + dt)*8 + ks)*512 + (size_t)lane*8]) = out;
}

// ---------------- K3b: Gaussian distance table ----------------
__global__ __launch_bounds__(256) void k3b_gt(const float* __restrict__ bias) {
    int idx = blockIdx.x * 256 + threadIdx.x;
    int h = idx / LL;
    int dist = idx - h*LL;
    float cm = bias[4*HH + h];
    float sig = cm*cm + 1e-4f;
    float dd = (float)dist;
    g_gt[idx] = __expf(-sig * dd * dd);
}

// ---------------- K4: MFMA implicit conv-GEMM ----------------
__global__ __launch_bounds__(256) void k4_mfma() {
    const int lt = blockIdx.x;
    const int b  = blockIdx.y;
    const int z  = blockIdx.z >> 1;
    const int dh = blockIdx.z & 1;
    const int fz = (z == 1) ? 1 : 0;
    const int t  = threadIdx.x;
    const int wave = t >> 6, lane = t & 63;
    const int l31 = lane & 31, khalf = lane >> 5;

    __shared__ __align__(16) unsigned short smem[128*128];  // 32 KB f tile (swizzled)

    const int wbeg = (wave == 0) ? 0 : 17 + (wave - 1)*16;
    const int wend = (wave == 0) ? 17 : wbeg + 16;

    f32x16 acc0, acc1;
    #pragma unroll
    for (int i = 0; i < 16; ++i) { acc0[i] = 0.f; acc1[i] = 0.f; }

    for (int dti = 0; dti < 2; ++dti) {
        const int dt = dh*2 + dti;
        __syncthreads();
        const unsigned short* src =
            g_fpad + ((size_t)(fz*BB + b)*LPAD + lt*64) * DD + dt*128;
        #pragma unroll
        for (int c = 0; c < 8; ++c) {
            int q = c*256 + t;
            int row = q >> 4, slot = q & 15;
            int4 v = *reinterpret_cast<const int4*>(src + (size_t)row*DD + slot*8);
            int off = row*256 + ((slot*16) ^ ((row & 15) << 4));
            *reinterpret_cast<int4*>((char*)smem + off) = v;
        }
        __syncthreads();

        for (int w = wbeg; w < wend; ++w) {
            const unsigned short* kbw =
                g_kb2 + ((((size_t)z*WW + w)*4 + dt)*8)*512;
            const int r0 = l31 + w;
            const int r1 = r0 + 32;
            #pragma unroll
            for (int ks = 0; ks < 8; ++ks) {
                bf16x8 bf = *reinterpret_cast<const bf16x8*>(kbw + ks*512 + lane*8);
                int dby = ks*32 + khalf*16;
                bf16x8 a0 = *reinterpret_cast<const bf16x8*>(
                    (char*)smem + r0*256 + (dby ^ ((r0 & 15) << 4)));
                bf16x8 a1 = *reinterpret_cast<const bf16x8*>(
                    (char*)smem + r1*256 + (dby ^ ((r1 & 15) << 4)));
                acc0 = __builtin_amdgcn_mfma_f32_32x32x16_bf16(a0, bf, acc0, 0, 0, 0);
                acc1 = __builtin_amdgcn_mfma_f32_32x32x16_bf16(a1, bf, acc1, 0, 0, 0);
            }
        }
    }

    float* outp = g_actsp[dh*4 + wave] + (size_t)z*BLH + ((size_t)b*LL + lt*64)*HH;
    #pragma unroll
    for (int reg = 0; reg < 16; ++reg) {
        int row = (reg & 3) + 8*(reg >> 2) + 4*khalf;
        outp[(size_t)row*HH + l31]        = acc0[reg];
        outp[(size_t)(32 + row)*HH + l31] = acc1[reg];
    }
}

// ---------------- K5: small GEMMs via MFMA (M=4096, N=32, K=512) ----------------
// grid (mt=32, o=4); block 256 = 4 waves; wave = one 32-row m-subtile.
__global__ __launch_bounds__(256) void k5_mfma() {
    const int mt = blockIdx.x;
    const int o  = blockIdx.y;
    const int t  = threadIdx.x;
    const int wave = t >> 6, lane = t & 63;
    const int l31 = lane & 31, khalf = lane >> 5;

    __shared__ __align__(16) unsigned short smem[128*128];  // 32 KB A tile (swizzled)

    const unsigned short* src;
    if (o == 3) {
        src = g_oefb + (size_t)mt*128*FCC;
    } else {
        const int fz = (o == 1) ? 0 : 1;
        const int m0 = mt*128;
        const int b_ = m0 >> 10, l0 = m0 & 1023;
        src = g_fpad + ((size_t)(fz*BB + b_)*LPAD + 32 + l0)*DD;
    }

    f32x16 acc;
    #pragma unroll
    for (int i = 0; i < 16; ++i) acc[i] = 0.f;

    for (int kc = 0; kc < 4; ++kc) {
        __syncthreads();
        const unsigned short* s2 = src + kc*128;   // row stride 512 for all sources
        #pragma unroll
        for (int c = 0; c < 8; ++c) {
            int q = c*256 + t;
            int row = q >> 4, slot = q & 15;
            int4 v = *reinterpret_cast<const int4*>(s2 + (size_t)row*512 + slot*8);
            int off = row*256 + ((slot*16) ^ ((row & 15) << 4));
            *reinterpret_cast<int4*>((char*)smem + off) = v;
        }
        __syncthreads();
        #pragma unroll
        for (int ks = 0; ks < 8; ++ks) {
            bf16x8 bf = *reinterpret_cast<const bf16x8*>(
                &g_kbs[((((size_t)o*4 + kc)*8 + ks)*64 + lane)*8]);
            int dby = ks*32 + khalf*16;
            int r = wave*32 + l31;
            bf16x8 a = *reinterpret_cast<const bf16x8*>(
                (char*)smem + r*256 + (dby ^ ((r & 15) << 4)));
            acc = __builtin_amdgcn_mfma_f32_32x32x16_bf16(a, bf, acc, 0, 0, 0);
        }
    }

    float* outp = g_small + (size_t)o*BLH + ((size_t)mt*128 + wave*32)*HH;
    #pragma unroll
    for (int reg = 0; reg < 16; ++reg) {
        int row = (reg & 3) + 8*(reg >> 2) + 4*khalf;
        outp[(size_t)row*HH + l31] = acc[reg];
    }
}

// ---------------- K6: Toeplitz mask correction ----------------
__global__ __launch_bounds__(256) void k6_vc() {
    __shared__ float ml[LL];
    const int b = blockIdx.y;
    for (int j = threadIdx.x; j < LL; j += 256) ml[j] = g_m[b*LL + j];
    __syncthreads();
    const int i = blockIdx.x * 8 + (threadIdx.x & 7);
    const int h = threadIdx.x >> 3;
    const float* __restrict__ gt = g_gt + (size_t)h * LL;
    float acc = 0.f;
    #pragma unroll 4
    for (int j = 0; j < LL; ++j) {
        int dd = i - j; dd = dd < 0 ? -dd : dd;
        acc = fmaf(gt[dd], ml[j], acc);
    }
    g_vsum[(size_t)(b*LL + i)*HH + h] = acc;
}

// ---------------- K7: final combine (sums the 8 conv partial slots) ----------------
__global__ __launch_bounds__(256) void k7_final(const float* __restrict__ masks,
                                                const float* __restrict__ bias,
                                                float* __restrict__ out) {
    int idx = blockIdx.x * 256 + threadIdx.x;
    int r = idx >> 5, h = idx & 31;
    float a0 = 0.f, a1 = 0.f, a2 = 0.f;
    #pragma unroll
    for (int s = 0; s < 8; ++s) {
        a0 += g_actsp[s][idx];
        a1 += g_actsp[s][BLH + idx];
        a2 += g_actsp[s][2*BLH + idx];
    }
    float rdf = (a0 + bias[0*HH + h]) * a1
              + a2 * (g_small[idx] + bias[2*HH + h])
              + (g_small[BLH + idx] + bias[1*HH + h]) * g_small[2*BLH + idx];
    float pp = g_small[3*BLH + idx] + bias[3*HH + h];
    float vc = g_m[r] * g_vsum[idx];
    out[idx] = vc * pp * rdf * masks[r];
}

extern "C" void kernel_launch(void* const* d_in, const int* in_sizes, int n_in,
                              void* d_out, int out_size, void* d_ws, size_t ws_size,
                              hipStream_t stream) {
    (void)in_sizes; (void)n_in; (void)d_ws; (void)ws_size; (void)out_size;
    const float* x_embeds = (const float*)d_in[0];
    const float* latent   = (const float*)d_in[1];
    const float* masks    = (const float*)d_in[2];
    const float* pos      = (const float*)d_in[3];
    const float* x        = (const float*)d_in[4];
    const float* ampl     = (const float*)d_in[5];
    const float* inp      = (const float*)d_in[6];
    const float* outv     = (const float*)d_in[7];
    const float* bias     = (const float*)d_in[8];
    const float* pdw      = (const float*)d_in[9];
    const float* knn      = (const float*)d_in[10];
    float* out = (float*)d_out;

    hipLaunchKernelGGL(k1_prep, dim3(BL/8), dim3(256), 0, stream, x_embeds, latent, masks, x);
    hipLaunchKernelGGL(k0_zero, dim3(128), dim3(256), 0, stream);
    hipLaunchKernelGGL(k3c_knt, dim3(8, 8, 2), dim3(256), 0, stream, knn);
    hipLaunchKernelGGL(k3d_kbs, dim3(32), dim3(256), 0, stream, ampl, pdw);
    hipLaunchKernelGGL(k3_kb2, dim3(8, WW, 3), dim3(256), 0, stream, ampl, inp, outv, pos);
    hipLaunchKernelGGL(k3b_gt, dim3(HH*LL/256), dim3(256), 0, stream, bias);
    hipLaunchKernelGGL(k2_mfma, dim3(4, 32, 2), dim3(256), 0, stream);
    hipLaunchKernelGGL(k4_mfma, dim3(16, BB, 6), dim3(256), 0, stream);
    hipLaunchKernelGGL(k5_mfma, dim3(32, 4), dim3(256), 0, stream);
    hipLaunchKernelGGL(k6_vc, dim3(LL/8, BB), dim3(256), 0, stream);
    hipLaunchKernelGGL(k7_final, dim3(BLH/256), dim3(256), 0, stream, masks, bias, out);
}

// Round 6
// 122.947 us; speedup vs baseline: 19.8048x; 1.2129x over previous
//
#include <hip/hip_runtime.h>
#include <hip/hip_bf16.h>

// Problem constants
#define BB 4
#define LL 1024
#define NFE 480
#define HH 32
#define FCC 512
#define DD 512
#define WW 65
#define BL (BB*LL)          // 4096
#define BLH (BL*HH)         // 131072
#define LPAD 1088           // 1024 + 2*32 halo

typedef short bf16x8 __attribute__((ext_vector_type(8)));
typedef float f32x16 __attribute__((ext_vector_type(16)));
typedef unsigned short us8 __attribute__((ext_vector_type(8)));
typedef unsigned short us4 __attribute__((ext_vector_type(4)));

__device__ inline unsigned short f2bf(float x) {
    union { float f; unsigned u; } v; v.f = x;
    unsigned r = v.u + 0x7FFFu + ((v.u >> 16) & 1u);
    return (unsigned short)(r >> 16);
}
__device__ inline float bf2f(unsigned short u) {
    union { unsigned u; float f; } v; v.u = ((unsigned)u) << 16;
    return v.f;
}

// Static device scratch
__device__ __align__(16) unsigned short g_oefb[BL*FCC];   // bf16 concat(x_embeds, cls)
__device__ __align__(16) unsigned short g_knt[2*DD*FCC];  // bf16 knn^T [z][n][k]
__device__ float  g_m[BL];
__device__ __align__(16) unsigned short g_fpad[2*BB*LPAD*DD];   // bf16 cf0/cf1, zero-padded rows
__device__ __align__(16) unsigned short g_kb2[(size_t)3*WW*4*8*64*8]; // conv k in B-frag order
__device__ __align__(16) unsigned short g_kbs[4*4*8*64*8];      // small-GEMM B in frag order
__device__ float  g_actsp[16][3*BLH];   // per-(dq,wave) partials: slot = dq*4+wave
__device__ float  g_small[4*BLH];
__device__ float  g_gt[HH*LL];
__device__ float  g_vsum[BLH];

// ---------------- K1: softmax + concat (bf16) + m ----------------
__global__ __launch_bounds__(256) void k1_prep(const float* __restrict__ x_embeds,
                                               const float* __restrict__ latent,
                                               const float* __restrict__ masks,
                                               const float* __restrict__ x) {
    const int tid  = threadIdx.x;
    const int row0 = blockIdx.x * 8;
    const int r    = row0 + (tid >> 5);
    const int lane = tid & 31;

    const float mask = masks[r];
    float v = latent[r*HH + lane] * mask;
    float mx = v;
    #pragma unroll
    for (int off = 16; off > 0; off >>= 1) mx = fmaxf(mx, __shfl_xor(mx, off, 32));
    float e = __expf(v - mx);
    float s = e;
    #pragma unroll
    for (int off = 16; off > 0; off >>= 1) s += __shfl_xor(s, off, 32);
    g_oefb[r*FCC + NFE + lane] = f2bf(e / s * mask);

    if (lane == 0) g_m[r] = mask + x[r*23 + 21] + x[r*23 + 22];

    for (int idx = tid; idx < 8*NFE; idx += 256) {
        int rr = idx / NFE, c = idx - rr*NFE;
        g_oefb[(row0+rr)*FCC + c] = f2bf(x_embeds[(row0+rr)*NFE + c]);
    }
}

// ---------------- K0: zero the halo rows of g_fpad ----------------
__global__ __launch_bounds__(256) void k0_zero() {
    int idx = blockIdx.x * 256 + threadIdx.x;       // < 32768 chunks of 16B
    int fzb = idx >> 12;                            // 0..7  (fz*4+b)
    int rem = idx & 4095;
    int rowi = rem >> 6;                            // 0..63
    int col8 = rem & 63;
    int row = (rowi < 32) ? rowi : (1024 + rowi);   // 0..31 or 1056..1087
    int4 z = make_int4(0,0,0,0);
    *reinterpret_cast<int4*>(&g_fpad[((size_t)fzb*LPAD + row)*DD + col8*8]) = z;
}

// ---------------- K3c: knn -> bf16 transpose g_knt[z][n][k] ----------------
__global__ __launch_bounds__(256) void k3c_knt(const float* __restrict__ knn) {
    __shared__ unsigned short tile[64][65];
    const int z  = blockIdx.z;
    const int k0 = blockIdx.x * 64;
    const int n0 = blockIdx.y * 64;
    const float* __restrict__ src = knn + (size_t)z*FCC*DD;
    #pragma unroll 4
    for (int i = 0; i < 16; ++i) {
        int idx = i*256 + threadIdx.x;
        int kk = idx >> 6, nn = idx & 63;
        tile[kk][nn] = f2bf(src[(size_t)(k0+kk)*DD + n0+nn]);
    }
    __syncthreads();
    #pragma unroll 4
    for (int i = 0; i < 16; ++i) {
        int idx = i*256 + threadIdx.x;
        int nn = idx >> 6, kk = idx & 63;
        g_knt[((size_t)z*DD + n0+nn)*FCC + k0+kk] = tile[kk][nn];
    }
}

// ---------------- K3d: small-GEMM B matrices -> frag order [o][dt][ks][lane][8] ----------------
__global__ __launch_bounds__(256) void k3d_kbs(const float* __restrict__ ampl,
                                               const float* __restrict__ pdw) {
    int t = blockIdx.x*256 + threadIdx.x;   // 0..8191
    int lane = t & 63;
    int ks = (t >> 6) & 7;
    int dt = (t >> 9) & 3;
    int o  = t >> 11;
    int l31 = lane & 31, khalf = lane >> 5;
    const float* S = (o == 0) ? ampl + 1*DD*HH :
                     (o == 1) ? ampl + 3*DD*HH :
                     (o == 2) ? ampl + 4*DD*HH : pdw;
    int k0 = dt*128 + ks*16 + khalf*8;
    us8 out;
    #pragma unroll
    for (int i = 0; i < 8; ++i) out[i] = f2bf(S[(size_t)(k0+i)*HH + l31]);
    *reinterpret_cast<us8*>(&g_kbs[(size_t)t*8]) = out;
}

// ---------------- K2: cf0/cf1 via MFMA, bf16 in/out ----------------
// grid (nt=4, mt=64, z=2) = 512 blocks; block 256 = 4 waves; wave = n-quadrant (32 cols)
// each wave: 2 m-subtiles of 32 rows; K=512 in 4 LDS-staged chunks of 128.
__global__ __launch_bounds__(256) void k2_mfma() {
    const int nt = blockIdx.x;
    const int mt = blockIdx.y;
    const int z  = blockIdx.z;
    const int t  = threadIdx.x;
    const int wave = t >> 6, lane = t & 63;
    const int l31 = lane & 31, khalf = lane >> 5;
    const int n0 = nt*128 + wave*32;
    const int m_base = mt*64;

    __shared__ __align__(16) unsigned short smem[64*128];  // 16 KB A tile (swizzled)

    f32x16 acc[2];
    #pragma unroll
    for (int mti = 0; mti < 2; ++mti)
        #pragma unroll
        for (int i = 0; i < 16; ++i) acc[mti][i] = 0.f;

    const unsigned short* __restrict__ bptr =
        g_knt + ((size_t)z*DD + n0 + l31)*FCC + khalf*8;

    for (int kc = 0; kc < 4; ++kc) {
        __syncthreads();
        const unsigned short* __restrict__ src = g_oefb + (size_t)m_base*FCC + kc*128;
        #pragma unroll
        for (int c = 0; c < 4; ++c) {
            int q = c*256 + t;
            int row = q >> 4, slot = q & 15;
            int4 v = *reinterpret_cast<const int4*>(src + (size_t)row*FCC + slot*8);
            int off = row*256 + ((slot*16) ^ ((row & 15) << 4));
            *reinterpret_cast<int4*>((char*)smem + off) = v;
        }
        __syncthreads();
        #pragma unroll
        for (int ks = 0; ks < 8; ++ks) {
            bf16x8 bf = *reinterpret_cast<const bf16x8*>(bptr + kc*128 + ks*16);
            int dby = ks*32 + khalf*16;
            #pragma unroll
            for (int mti = 0; mti < 2; ++mti) {
                int r = mti*32 + l31;
                bf16x8 a = *reinterpret_cast<const bf16x8*>(
                    (char*)smem + r*256 + (dby ^ ((r & 15) << 4)));
                acc[mti] = __builtin_amdgcn_mfma_f32_32x32x16_bf16(a, bf, acc[mti], 0, 0, 0);
            }
        }
    }

    #pragma unroll
    for (int mti = 0; mti < 2; ++mti) {
        #pragma unroll
        for (int reg = 0; reg < 16; ++reg) {
            int rowf = (reg & 3) + 8*(reg >> 2) + 4*khalf;
            int m = m_base + mti*32 + rowf;
            int b_ = m >> 10, l_ = m & 1023;
            g_fpad[((size_t)(z*BB + b_)*LPAD + 32 + l_)*DD + n0 + l31] = f2bf(acc[mti][reg]);
        }
    }
}

// ---------------- K3: build conv k in MFMA B-frag order ----------------
__global__ __launch_bounds__(256) void k3_kb2(const float* __restrict__ ampl,
                                              const float* __restrict__ inp,
                                              const float* __restrict__ outv,
                                              const float* __restrict__ pos) {
    const int z = blockIdx.z;
    const int w = blockIdx.y;
    const int idx = blockIdx.x * 256 + threadIdx.x;   // 0..2047 within (z,w)
    const int lane = idx & 63;
    const int ks   = (idx >> 6) & 7;
    const int dt   = idx >> 9;
    const int h    = lane & 31;
    const int d8   = dt*128 + ks*16 + (lane >> 5)*8;

    const float c0 = 0.01f;
    const float p = pos[w];
    int ai, mi, vi;
    if (z == 0)      { ai = 0; mi = 0;  vi = 1; }
    else if (z == 1) { ai = 1; mi = -1; vi = 2; }
    else             { ai = 2; mi = 3;  vi = 4; }

    us8 out;
    #pragma unroll
    for (int i = 0; i < 8; ++i) {
        int d = d8 + i;
        float a    = ampl[(size_t)ai*DD*HH + d*HH + h];
        float mean = (mi >= 0) ? inp[mi*DD + d] * outv[mi*HH + h] : 0.f;
        float iv   = fabsf(inp[vi*DD + d] * outv[vi*HH + h]) + c0;
        float tt = p - mean;
        out[i] = f2bf(__expf(-iv * tt * tt) * a);
    }
    *reinterpret_cast<us8*>(&g_kb2[((((size_t)z*WW + w)*4 + dt)*8 + ks)*512 + (size_t)lane*8]) = out;
}

// ---------------- K3b: Gaussian distance table ----------------
__global__ __launch_bounds__(256) void k3b_gt(const float* __restrict__ bias) {
    int idx = blockIdx.x * 256 + threadIdx.x;
    int h = idx / LL;
    int dist = idx - h*LL;
    float cm = bias[4*HH + h];
    float sig = cm*cm + 1e-4f;
    float dd = (float)dist;
    g_gt[idx] = __expf(-sig * dd * dd);
}

// ---------------- K4: MFMA implicit conv-GEMM ----------------
// grid: (ltile=16, b=4, z*4+dq=12) = 768 blocks; block 256 = 4 waves
// wave = one w-quarter; each (dq,wave) writes its OWN partial slot (summed in k7).
__global__ __launch_bounds__(256) void k4_mfma() {
    const int lt = blockIdx.x;
    const int b  = blockIdx.y;
    const int z  = blockIdx.z >> 2;
    const int dq = blockIdx.z & 3;
    const int fz = (z == 1) ? 1 : 0;
    const int t  = threadIdx.x;
    const int wave = t >> 6, lane = t & 63;
    const int l31 = lane & 31, khalf = lane >> 5;

    __shared__ __align__(16) unsigned short smem[128*128];  // 32 KB f tile (swizzled)

    const int wbeg = (wave == 0) ? 0 : 17 + (wave - 1)*16;
    const int wend = (wave == 0) ? 17 : wbeg + 16;

    f32x16 acc0, acc1;
    #pragma unroll
    for (int i = 0; i < 16; ++i) { acc0[i] = 0.f; acc1[i] = 0.f; }

    // stage f tile: rows lt*64 .. +127 (padded space), cols dq*128..+127
    const unsigned short* src =
        g_fpad + ((size_t)(fz*BB + b)*LPAD + lt*64) * DD + dq*128;
    #pragma unroll
    for (int c = 0; c < 8; ++c) {
        int q = c*256 + t;
        int row = q >> 4, slot = q & 15;
        int4 v = *reinterpret_cast<const int4*>(src + (size_t)row*DD + slot*8);
        int off = row*256 + ((slot*16) ^ ((row & 15) << 4));
        *reinterpret_cast<int4*>((char*)smem + off) = v;
    }
    __syncthreads();

    for (int w = wbeg; w < wend; ++w) {
        const unsigned short* kbw =
            g_kb2 + ((((size_t)z*WW + w)*4 + dq)*8)*512;
        const int r0 = l31 + w;
        const int r1 = r0 + 32;
        #pragma unroll
        for (int ks = 0; ks < 8; ++ks) {
            bf16x8 bf = *reinterpret_cast<const bf16x8*>(kbw + ks*512 + lane*8);
            int dby = ks*32 + khalf*16;
            bf16x8 a0 = *reinterpret_cast<const bf16x8*>(
                (char*)smem + r0*256 + (dby ^ ((r0 & 15) << 4)));
            bf16x8 a1 = *reinterpret_cast<const bf16x8*>(
                (char*)smem + r1*256 + (dby ^ ((r1 & 15) << 4)));
            acc0 = __builtin_amdgcn_mfma_f32_32x32x16_bf16(a0, bf, acc0, 0, 0, 0);
            acc1 = __builtin_amdgcn_mfma_f32_32x32x16_bf16(a1, bf, acc1, 0, 0, 0);
        }
    }

    float* outp = g_actsp[dq*4 + wave] + (size_t)z*BLH + ((size_t)b*LL + lt*64)*HH;
    #pragma unroll
    for (int reg = 0; reg < 16; ++reg) {
        int row = (reg & 3) + 8*(reg >> 2) + 4*khalf;
        outp[(size_t)row*HH + l31]        = acc0[reg];
        outp[(size_t)(32 + row)*HH + l31] = acc1[reg];
    }
}

// ---------------- K5: small GEMMs via MFMA (M=4096, N=32, K=512) ----------------
// grid (mt=32, o=4); block 256 = 4 waves; wave = one 32-row m-subtile.
__global__ __launch_bounds__(256) void k5_mfma() {
    const int mt = blockIdx.x;
    const int o  = blockIdx.y;
    const int t  = threadIdx.x;
    const int wave = t >> 6, lane = t & 63;
    const int l31 = lane & 31, khalf = lane >> 5;

    __shared__ __align__(16) unsigned short smem[128*128];  // 32 KB A tile (swizzled)

    const unsigned short* src;
    if (o == 3) {
        src = g_oefb + (size_t)mt*128*FCC;
    } else {
        const int fz = (o == 1) ? 0 : 1;
        const int m0 = mt*128;
        const int b_ = m0 >> 10, l0 = m0 & 1023;
        src = g_fpad + ((size_t)(fz*BB + b_)*LPAD + 32 + l0)*DD;
    }

    f32x16 acc;
    #pragma unroll
    for (int i = 0; i < 16; ++i) acc[i] = 0.f;

    for (int kc = 0; kc < 4; ++kc) {
        __syncthreads();
        const unsigned short* s2 = src + kc*128;   // row stride 512 for all sources
        #pragma unroll
        for (int c = 0; c < 8; ++c) {
            int q = c*256 + t;
            int row = q >> 4, slot = q & 15;
            int4 v = *reinterpret_cast<const int4*>(s2 + (size_t)row*512 + slot*8);
            int off = row*256 + ((slot*16) ^ ((row & 15) << 4));
            *reinterpret_cast<int4*>((char*)smem + off) = v;
        }
        __syncthreads();
        #pragma unroll
        for (int ks = 0; ks < 8; ++ks) {
            bf16x8 bf = *reinterpret_cast<const bf16x8*>(
                &g_kbs[((((size_t)o*4 + kc)*8 + ks)*64 + lane)*8]);
            int dby = ks*32 + khalf*16;
            int r = wave*32 + l31;
            bf16x8 a = *reinterpret_cast<const bf16x8*>(
                (char*)smem + r*256 + (dby ^ ((r & 15) << 4)));
            acc = __builtin_amdgcn_mfma_f32_32x32x16_bf16(a, bf, acc, 0, 0, 0);
        }
    }

    float* outp = g_small + (size_t)o*BLH + ((size_t)mt*128 + wave*32)*HH;
    #pragma unroll
    for (int reg = 0; reg < 16; ++reg) {
        int row = (reg & 3) + 8*(reg >> 2) + 4*khalf;
        outp[(size_t)row*HH + l31] = acc[reg];
    }
}

// ---------------- K6: Toeplitz mask correction ----------------
__global__ __launch_bounds__(256) void k6_vc() {
    __shared__ float ml[LL];
    const int b = blockIdx.y;
    for (int j = threadIdx.x; j < LL; j += 256) ml[j] = g_m[b*LL + j];
    __syncthreads();
    const int i = blockIdx.x * 8 + (threadIdx.x & 7);
    const int h = threadIdx.x >> 3;
    const float* __restrict__ gt = g_gt + (size_t)h * LL;
    float acc = 0.f;
    #pragma unroll 4
    for (int j = 0; j < LL; ++j) {
        int dd = i - j; dd = dd < 0 ? -dd : dd;
        acc = fmaf(gt[dd], ml[j], acc);
    }
    g_vsum[(size_t)(b*LL + i)*HH + h] = acc;
}

// ---------------- K7: final combine (sums the 16 conv partial slots) ----------------
__global__ __launch_bounds__(256) void k7_final(const float* __restrict__ masks,
                                                const float* __restrict__ bias,
                                                float* __restrict__ out) {
    int idx = blockIdx.x * 256 + threadIdx.x;
    int r = idx >> 5, h = idx & 31;
    float a0 = 0.f, a1 = 0.f, a2 = 0.f;
    #pragma unroll
    for (int s = 0; s < 16; ++s) {
        a0 += g_actsp[s][idx];
        a1 += g_actsp[s][BLH + idx];
        a2 += g_actsp[s][2*BLH + idx];
    }
    float rdf = (a0 + bias[0*HH + h]) * a1
              + a2 * (g_small[idx] + bias[2*HH + h])
              + (g_small[BLH + idx] + bias[1*HH + h]) * g_small[2*BLH + idx];
    float pp = g_small[3*BLH + idx] + bias[3*HH + h];
    float vc = g_m[r] * g_vsum[idx];
    out[idx] = vc * pp * rdf * masks[r];
}

extern "C" void kernel_launch(void* const* d_in, const int* in_sizes, int n_in,
                              void* d_out, int out_size, void* d_ws, size_t ws_size,
                              hipStream_t stream) {
    (void)in_sizes; (void)n_in; (void)d_ws; (void)ws_size; (void)out_size;
    const float* x_embeds = (const float*)d_in[0];
    const float* latent   = (const float*)d_in[1];
    const float* masks    = (const float*)d_in[2];
    const float* pos      = (const float*)d_in[3];
    const float* x        = (const float*)d_in[4];
    const float* ampl     = (const float*)d_in[5];
    const float* inp      = (const float*)d_in[6];
    const float* outv     = (const float*)d_in[7];
    const float* bias     = (const float*)d_in[8];
    const float* pdw      = (const float*)d_in[9];
    const float* knn      = (const float*)d_in[10];
    float* out = (float*)d_out;

    hipLaunchKernelGGL(k1_prep, dim3(BL/8), dim3(256), 0, stream, x_embeds, latent, masks, x);
    hipLaunchKernelGGL(k0_zero, dim3(128), dim3(256), 0, stream);
    hipLaunchKernelGGL(k3c_knt, dim3(8, 8, 2), dim3(256), 0, stream, knn);
    hipLaunchKernelGGL(k3d_kbs, dim3(32), dim3(256), 0, stream, ampl, pdw);
    hipLaunchKernelGGL(k3_kb2, dim3(8, WW, 3), dim3(256), 0, stream, ampl, inp, outv, pos);
    hipLaunchKernelGGL(k3b_gt, dim3(HH*LL/256), dim3(256), 0, stream, bias);
    hipLaunchKernelGGL(k2_mfma, dim3(4, 64, 2), dim3(256), 0, stream);
    hipLaunchKernelGGL(k4_mfma, dim3(16, BB, 12), dim3(256), 0, stream);
    hipLaunchKernelGGL(k5_mfma, dim3(32, 4), dim3(256), 0, stream);
    hipLaunchKernelGGL(k6_vc, dim3(LL/8, BB), dim3(256), 0, stream);
    hipLaunchKernelGGL(k7_final, dim3(BLH/256), dim3(256), 0, stream, masks, bias, out);
}

// Round 7
// 99.444 us; speedup vs baseline: 24.4855x; 1.2363x over previous
//
#include <hip/hip_runtime.h>
#include <hip/hip_bf16.h>

// Problem constants
#define BB 4
#define LL 1024
#define NFE 480
#define HH 32
#define FCC 512
#define DD 512
#define WW 65
#define BL (BB*LL)          // 4096
#define BLH (BL*HH)         // 131072
#define LPAD 1088           // 1024 + 2*32 halo

typedef short bf16x8 __attribute__((ext_vector_type(8)));
typedef float f32x16 __attribute__((ext_vector_type(16)));
typedef unsigned short us8 __attribute__((ext_vector_type(8)));

__device__ inline unsigned short f2bf(float x) {
    union { float f; unsigned u; } v; v.f = x;
    unsigned r = v.u + 0x7FFFu + ((v.u >> 16) & 1u);
    return (unsigned short)(r >> 16);
}

// Static device scratch
__device__ __align__(16) unsigned short g_oefb[BL*FCC];   // bf16 concat(x_embeds, cls)
__device__ __align__(16) unsigned short g_knt[2*DD*FCC];  // bf16 knn^T [z][n][k]
__device__ float  g_m[BL];
__device__ __align__(16) unsigned short g_fpad[2*BB*LPAD*DD];   // bf16 cf0/cf1, zero-padded rows
__device__ __align__(16) unsigned short g_kb2[(size_t)3*WW*4*8*64*8]; // conv k in B-frag order
__device__ __align__(16) unsigned short g_kbs[4*4*8*64*8];      // small-GEMM B in frag order
__device__ float  g_actsp[4][3*BLH];    // per-dq partials (waves pre-reduced in-block)
__device__ float  g_small[4*BLH];
__device__ float  g_gt[HH*LL];
__device__ float  g_vsum[BLH];

// ================ KPREP: fused k1_prep / k0_zero / k3c_knt / k3d_kbs / k3b_gt / k3_kb2 ================
// flat grid 2488 blocks:
//   [0,512)     k1_prep     [512,640)  k0_zero    [640,768)  k3c_knt
//   [768,800)   k3d_kbs     [800,928)  k3b_gt     [928,2488) k3_kb2
__global__ __launch_bounds__(256) void kprep(const float* __restrict__ x_embeds,
                                             const float* __restrict__ latent,
                                             const float* __restrict__ masks,
                                             const float* __restrict__ x,
                                             const float* __restrict__ ampl,
                                             const float* __restrict__ inp,
                                             const float* __restrict__ outv,
                                             const float* __restrict__ pos,
                                             const float* __restrict__ bias,
                                             const float* __restrict__ pdw,
                                             const float* __restrict__ knn) {
    const int bx = blockIdx.x;
    const int tid = threadIdx.x;

    if (bx < 512) {                    // ---- k1: softmax + concat + m ----
        const int row0 = bx * 8;
        const int r    = row0 + (tid >> 5);
        const int lane = tid & 31;

        const float mask = masks[r];
        float v = latent[r*HH + lane] * mask;
        float mx = v;
        #pragma unroll
        for (int off = 16; off > 0; off >>= 1) mx = fmaxf(mx, __shfl_xor(mx, off, 32));
        float e = __expf(v - mx);
        float s = e;
        #pragma unroll
        for (int off = 16; off > 0; off >>= 1) s += __shfl_xor(s, off, 32);
        g_oefb[r*FCC + NFE + lane] = f2bf(e / s * mask);

        if (lane == 0) g_m[r] = mask + x[r*23 + 21] + x[r*23 + 22];

        for (int idx = tid; idx < 8*NFE; idx += 256) {
            int rr = idx / NFE, c = idx - rr*NFE;
            g_oefb[(row0+rr)*FCC + c] = f2bf(x_embeds[(row0+rr)*NFE + c]);
        }
    } else if (bx < 640) {             // ---- k0: zero g_fpad halos ----
        int idx = (bx - 512) * 256 + tid;
        int fzb = idx >> 12;
        int rem = idx & 4095;
        int rowi = rem >> 6;
        int col8 = rem & 63;
        int row = (rowi < 32) ? rowi : (1024 + rowi);
        int4 z = make_int4(0,0,0,0);
        *reinterpret_cast<int4*>(&g_fpad[((size_t)fzb*LPAD + row)*DD + col8*8]) = z;
    } else if (bx < 768) {             // ---- k3c: knn -> bf16 transpose ----
        __shared__ unsigned short tile[64][65];
        int idx2 = bx - 640;
        const int k0 = (idx2 & 7) * 64;
        const int n0 = ((idx2 >> 3) & 7) * 64;
        const int z  = idx2 >> 6;
        const float* __restrict__ src = knn + (size_t)z*FCC*DD;
        #pragma unroll 4
        for (int i = 0; i < 16; ++i) {
            int idx = i*256 + tid;
            int kk = idx >> 6, nn = idx & 63;
            tile[kk][nn] = f2bf(src[(size_t)(k0+kk)*DD + n0+nn]);
        }
        __syncthreads();
        #pragma unroll 4
        for (int i = 0; i < 16; ++i) {
            int idx = i*256 + tid;
            int nn = idx >> 6, kk = idx & 63;
            g_knt[((size_t)z*DD + n0+nn)*FCC + k0+kk] = tile[kk][nn];
        }
    } else if (bx < 800) {             // ---- k3d: small-GEMM B frags ----
        int t = (bx - 768)*256 + tid;
        int lane = t & 63;
        int ks = (t >> 6) & 7;
        int dt = (t >> 9) & 3;
        int o  = t >> 11;
        int l31 = lane & 31, khalf = lane >> 5;
        const float* S = (o == 0) ? ampl + 1*DD*HH :
                         (o == 1) ? ampl + 3*DD*HH :
                         (o == 2) ? ampl + 4*DD*HH : pdw;
        int k0 = dt*128 + ks*16 + khalf*8;
        us8 outw;
        #pragma unroll
        for (int i = 0; i < 8; ++i) outw[i] = f2bf(S[(size_t)(k0+i)*HH + l31]);
        *reinterpret_cast<us8*>(&g_kbs[(size_t)t*8]) = outw;
    } else if (bx < 928) {             // ---- k3b: Gaussian distance table ----
        int idx = (bx - 800) * 256 + tid;
        int h = idx / LL;
        int dist = idx - h*LL;
        float cm = bias[4*HH + h];
        float sig = cm*cm + 1e-4f;
        float dd = (float)dist;
        g_gt[idx] = __expf(-sig * dd * dd);
    } else {                           // ---- k3: conv k in B-frag order ----
        int idx3 = bx - 928;           // 0..1559
        int xi  = idx3 & 7;
        int rem = idx3 >> 3;           // 0..194
        int w   = rem % 65;
        int z   = rem / 65;
        int idx = xi * 256 + tid;      // 0..2047
        const int lane = idx & 63;
        const int ks   = (idx >> 6) & 7;
        const int dt   = idx >> 9;
        const int h    = lane & 31;
        const int d8   = dt*128 + ks*16 + (lane >> 5)*8;

        const float c0 = 0.01f;
        const float p = pos[w];
        int ai, mi, vi;
        if (z == 0)      { ai = 0; mi = 0;  vi = 1; }
        else if (z == 1) { ai = 1; mi = -1; vi = 2; }
        else             { ai = 2; mi = 3;  vi = 4; }

        us8 outw;
        #pragma unroll
        for (int i = 0; i < 8; ++i) {
            int d = d8 + i;
            float a    = ampl[(size_t)ai*DD*HH + d*HH + h];
            float mean = (mi >= 0) ? inp[mi*DD + d] * outv[mi*HH + h] : 0.f;
            float iv   = fabsf(inp[vi*DD + d] * outv[vi*HH + h]) + c0;
            float tt = p - mean;
            outw[i] = f2bf(__expf(-iv * tt * tt) * a);
        }
        *reinterpret_cast<us8*>(&g_kb2[((((size_t)z*WW + w)*4 + dt)*8 + ks)*512 + (size_t)lane*8]) = outw;
    }
}

// ================ K2: cf0/cf1 via MFMA, bf16 in/out ================
// grid (nt=4, mt=64, z=2) = 512 blocks; block 256 = 4 waves; wave = n-quadrant (32 cols)
__global__ __launch_bounds__(256) void k2_mfma() {
    const int nt = blockIdx.x;
    const int mt = blockIdx.y;
    const int z  = blockIdx.z;
    const int t  = threadIdx.x;
    const int wave = t >> 6, lane = t & 63;
    const int l31 = lane & 31, khalf = lane >> 5;
    const int n0 = nt*128 + wave*32;
    const int m_base = mt*64;

    __shared__ __align__(16) unsigned short smem[64*128];  // 16 KB A tile (swizzled)

    f32x16 acc[2];
    #pragma unroll
    for (int mti = 0; mti < 2; ++mti)
        #pragma unroll
        for (int i = 0; i < 16; ++i) acc[mti][i] = 0.f;

    const unsigned short* __restrict__ bptr =
        g_knt + ((size_t)z*DD + n0 + l31)*FCC + khalf*8;

    for (int kc = 0; kc < 4; ++kc) {
        __syncthreads();
        const unsigned short* __restrict__ src = g_oefb + (size_t)m_base*FCC + kc*128;
        #pragma unroll
        for (int c = 0; c < 4; ++c) {
            int q = c*256 + t;
            int row = q >> 4, slot = q & 15;
            int4 v = *reinterpret_cast<const int4*>(src + (size_t)row*FCC + slot*8);
            int off = row*256 + ((slot*16) ^ ((row & 15) << 4));
            *reinterpret_cast<int4*>((char*)smem + off) = v;
        }
        __syncthreads();
        #pragma unroll
        for (int ks = 0; ks < 8; ++ks) {
            bf16x8 bf = *reinterpret_cast<const bf16x8*>(bptr + kc*128 + ks*16);
            int dby = ks*32 + khalf*16;
            #pragma unroll
            for (int mti = 0; mti < 2; ++mti) {
                int r = mti*32 + l31;
                bf16x8 a = *reinterpret_cast<const bf16x8*>(
                    (char*)smem + r*256 + (dby ^ ((r & 15) << 4)));
                acc[mti] = __builtin_amdgcn_mfma_f32_32x32x16_bf16(a, bf, acc[mti], 0, 0, 0);
            }
        }
    }

    #pragma unroll
    for (int mti = 0; mti < 2; ++mti) {
        #pragma unroll
        for (int reg = 0; reg < 16; ++reg) {
            int rowf = (reg & 3) + 8*(reg >> 2) + 4*khalf;
            int m = m_base + mti*32 + rowf;
            int b_ = m >> 10, l_ = m & 1023;
            g_fpad[((size_t)(z*BB + b_)*LPAD + 32 + l_)*DD + n0 + l31] = f2bf(acc[mti][reg]);
        }
    }
}

// ================ KHEAVY: fused k4_mfma / k6_vc / k5_mfma ================
// flat grid 1408: [0,768) k4 roles; [768,1280) k6; [1280,1408) k5.
__global__ __launch_bounds__(256) void kheavy() {
    __shared__ __align__(16) char smem_raw[32768];
    const int bx = blockIdx.x;
    const int t  = threadIdx.x;

    if (bx < 768) {
        // ---------- k4: MFMA implicit conv-GEMM, in-block wave reduction ----------
        unsigned short* smem = (unsigned short*)smem_raw;
        const int lt = bx & 15;
        const int b  = (bx >> 4) & 3;
        const int zdq = bx >> 6;
        const int z  = zdq >> 2;
        const int dq = zdq & 3;
        const int fz = (z == 1) ? 1 : 0;
        const int wave = t >> 6, lane = t & 63;
        const int l31 = lane & 31, khalf = lane >> 5;

        const int wbeg = (wave == 0) ? 0 : 17 + (wave - 1)*16;
        const int wend = (wave == 0) ? 17 : wbeg + 16;

        f32x16 acc0, acc1;
        #pragma unroll
        for (int i = 0; i < 16; ++i) { acc0[i] = 0.f; acc1[i] = 0.f; }

        const unsigned short* src =
            g_fpad + ((size_t)(fz*BB + b)*LPAD + lt*64) * DD + dq*128;
        #pragma unroll
        for (int c = 0; c < 8; ++c) {
            int q = c*256 + t;
            int row = q >> 4, slot = q & 15;
            int4 v = *reinterpret_cast<const int4*>(src + (size_t)row*DD + slot*8);
            int off = row*256 + ((slot*16) ^ ((row & 15) << 4));
            *reinterpret_cast<int4*>(smem_raw + off) = v;
        }
        __syncthreads();

        for (int w = wbeg; w < wend; ++w) {
            const unsigned short* kbw =
                g_kb2 + ((((size_t)z*WW + w)*4 + dq)*8)*512;
            const int r0 = l31 + w;
            const int r1 = r0 + 32;
            #pragma unroll
            for (int ks = 0; ks < 8; ++ks) {
                bf16x8 bf = *reinterpret_cast<const bf16x8*>(kbw + ks*512 + lane*8);
                int dby = ks*32 + khalf*16;
                bf16x8 a0 = *reinterpret_cast<const bf16x8*>(
                    smem_raw + r0*256 + (dby ^ ((r0 & 15) << 4)));
                bf16x8 a1 = *reinterpret_cast<const bf16x8*>(
                    smem_raw + r1*256 + (dby ^ ((r1 & 15) << 4)));
                acc0 = __builtin_amdgcn_mfma_f32_32x32x16_bf16(a0, bf, acc0, 0, 0, 0);
                acc1 = __builtin_amdgcn_mfma_f32_32x32x16_bf16(a1, bf, acc1, 0, 0, 0);
            }
        }

        // in-block reduction across the 4 waves (w-quarters)
        __syncthreads();               // all smem A-tile reads done
        float* red = (float*)smem_raw; // 4 waves × 2048 floats = 32 KB
        #pragma unroll
        for (int reg = 0; reg < 16; ++reg) {
            int row = (reg & 3) + 8*(reg >> 2) + 4*khalf;
            red[wave*2048 + row*32 + l31]        = acc0[reg];
            red[wave*2048 + (32 + row)*32 + l31] = acc1[reg];
        }
        __syncthreads();
        float* outp = g_actsp[dq] + (size_t)z*BLH + ((size_t)b*LL + lt*64)*HH;
        #pragma unroll
        for (int j = 0; j < 8; ++j) {
            int i = j*256 + t;
            float sum = red[i] + red[2048 + i] + red[4096 + i] + red[6144 + i];
            outp[i] = sum;
        }
    } else if (bx < 1280) {
        // ---------- k6: Toeplitz mask correction ----------
        float* ml = (float*)smem_raw;  // 4 KB
        const int g = bx - 768;
        const int ib = g & 127;
        const int b  = g >> 7;
        for (int j = t; j < LL; j += 256) ml[j] = g_m[b*LL + j];
        __syncthreads();
        const int i = ib * 8 + (t & 7);
        const int h = t >> 3;
        const float* __restrict__ gt = g_gt + (size_t)h * LL;
        float acc = 0.f;
        #pragma unroll 4
        for (int j = 0; j < LL; ++j) {
            int dd = i - j; dd = dd < 0 ? -dd : dd;
            acc = fmaf(gt[dd], ml[j], acc);
        }
        g_vsum[(size_t)(b*LL + i)*HH + h] = acc;
    } else {
        // ---------- k5: small GEMMs via MFMA (M=4096, N=32, K=512) ----------
        unsigned short* smem = (unsigned short*)smem_raw;
        const int g = bx - 1280;
        const int mt = g & 31;
        const int o  = g >> 5;
        const int wave = t >> 6, lane = t & 63;
        const int l31 = lane & 31, khalf = lane >> 5;

        const unsigned short* src;
        if (o == 3) {
            src = g_oefb + (size_t)mt*128*FCC;
        } else {
            const int fz = (o == 1) ? 0 : 1;
            const int m0 = mt*128;
            const int b_ = m0 >> 10, l0 = m0 & 1023;
            src = g_fpad + ((size_t)(fz*BB + b_)*LPAD + 32 + l0)*DD;
        }

        f32x16 acc;
        #pragma unroll
        for (int i = 0; i < 16; ++i) acc[i] = 0.f;

        for (int kc = 0; kc < 4; ++kc) {
            __syncthreads();
            const unsigned short* s2 = src + kc*128;
            #pragma unroll
            for (int c = 0; c < 8; ++c) {
                int q = c*256 + t;
                int row = q >> 4, slot = q & 15;
                int4 v = *reinterpret_cast<const int4*>(s2 + (size_t)row*512 + slot*8);
                int off = row*256 + ((slot*16) ^ ((row & 15) << 4));
                *reinterpret_cast<int4*>(smem_raw + off) = v;
            }
            __syncthreads();
            #pragma unroll
            for (int ks = 0; ks < 8; ++ks) {
                bf16x8 bf = *reinterpret_cast<const bf16x8*>(
                    &g_kbs[((((size_t)o*4 + kc)*8 + ks)*64 + lane)*8]);
                int dby = ks*32 + khalf*16;
                int r = wave*32 + l31;
                bf16x8 a = *reinterpret_cast<const bf16x8*>(
                    smem_raw + r*256 + (dby ^ ((r & 15) << 4)));
                acc = __builtin_amdgcn_mfma_f32_32x32x16_bf16(a, bf, acc, 0, 0, 0);
            }
        }

        float* outp = g_small + (size_t)o*BLH + ((size_t)mt*128 + wave*32)*HH;
        #pragma unroll
        for (int reg = 0; reg < 16; ++reg) {
            int row = (reg & 3) + 8*(reg >> 2) + 4*khalf;
            outp[(size_t)row*HH + l31] = acc[reg];
        }
    }
}

// ================ K7: final combine (sums the 4 dq partial slots) ================
__global__ __launch_bounds__(256) void k7_final(const float* __restrict__ masks,
                                                const float* __restrict__ bias,
                                                float* __restrict__ out) {
    int idx = blockIdx.x * 256 + threadIdx.x;
    int r = idx >> 5, h = idx & 31;
    float a0 = 0.f, a1 = 0.f, a2 = 0.f;
    #pragma unroll
    for (int s = 0; s < 4; ++s) {
        a0 += g_actsp[s][idx];
        a1 += g_actsp[s][BLH + idx];
        a2 += g_actsp[s][2*BLH + idx];
    }
    float rdf = (a0 + bias[0*HH + h]) * a1
              + a2 * (g_small[idx] + bias[2*HH + h])
              + (g_small[BLH + idx] + bias[1*HH + h]) * g_small[2*BLH + idx];
    float pp = g_small[3*BLH + idx] + bias[3*HH + h];
    float vc = g_m[r] * g_vsum[idx];
    out[idx] = vc * pp * rdf * masks[r];
}

extern "C" void kernel_launch(void* const* d_in, const int* in_sizes, int n_in,
                              void* d_out, int out_size, void* d_ws, size_t ws_size,
                              hipStream_t stream) {
    (void)in_sizes; (void)n_in; (void)d_ws; (void)ws_size; (void)out_size;
    const float* x_embeds = (const float*)d_in[0];
    const float* latent   = (const float*)d_in[1];
    const float* masks    = (const float*)d_in[2];
    const float* pos      = (const float*)d_in[3];
    const float* x        = (const float*)d_in[4];
    const float* ampl     = (const float*)d_in[5];
    const float* inp      = (const float*)d_in[6];
    const float* outv     = (const float*)d_in[7];
    const float* bias     = (const float*)d_in[8];
    const float* pdw      = (const float*)d_in[9];
    const float* knn      = (const float*)d_in[10];
    float* out = (float*)d_out;

    hipLaunchKernelGGL(kprep, dim3(2488), dim3(256), 0, stream,
                       x_embeds, latent, masks, x, ampl, inp, outv, pos, bias, pdw, knn);
    hipLaunchKernelGGL(k2_mfma, dim3(4, 64, 2), dim3(256), 0, stream);
    hipLaunchKernelGGL(kheavy, dim3(1408), dim3(256), 0, stream);
    hipLaunchKernelGGL(k7_final, dim3(BLH/256), dim3(256), 0, stream, masks, bias, out);
}

// Round 8
// 88.470 us; speedup vs baseline: 27.5226x; 1.1240x over previous
//
#include <hip/hip_runtime.h>
#include <hip/hip_bf16.h>

// Problem constants
#define BB 4
#define LL 1024
#define NFE 480
#define HH 32
#define FCC 512
#define DD 512
#define WW 65
#define BL (BB*LL)          // 4096
#define BLH (BL*HH)         // 131072
#define LPAD 1088           // 1024 + 2*32 halo

typedef short bf16x8 __attribute__((ext_vector_type(8)));
typedef float f32x16 __attribute__((ext_vector_type(16)));
typedef unsigned short us8 __attribute__((ext_vector_type(8)));

__device__ inline unsigned short f2bf(float x) {
    union { float f; unsigned u; } v; v.f = x;
    unsigned r = v.u + 0x7FFFu + ((v.u >> 16) & 1u);
    return (unsigned short)(r >> 16);
}

// Static device scratch
__device__ __align__(16) unsigned short g_oefb[BL*FCC];   // bf16 concat(x_embeds, cls)
__device__ __align__(16) unsigned short g_knt[2*DD*FCC];  // bf16 knn^T [z][n][k]
__device__ float  g_m[BL];
__device__ __align__(16) unsigned short g_fpad[2*BB*LPAD*DD];   // bf16 cf0/cf1, zero-padded rows
__device__ __align__(16) unsigned short g_kb2[(size_t)3*WW*4*8*64*8]; // conv k in B-frag order
__device__ __align__(16) unsigned short g_kbs[4*4*8*64*8];      // small-GEMM B in frag order
__device__ float  g_actsp[4][3*BLH];    // per-dq partials (waves pre-reduced in-block)
__device__ float  g_small[4*BLH];
__device__ float  g_gt[HH*LL];
__device__ float  g_vsum[BLH];

// ================ KPREP: fused k1_prep / k0_zero / k3c_knt / k3d_kbs / k3b_gt / k3_kb2 ================
// flat grid 2488 blocks:
//   [0,512)     k1_prep     [512,640)  k0_zero    [640,768)  k3c_knt
//   [768,800)   k3d_kbs     [800,928)  k3b_gt     [928,2488) k3_kb2
__global__ __launch_bounds__(256) void kprep(const float* __restrict__ x_embeds,
                                             const float* __restrict__ latent,
                                             const float* __restrict__ masks,
                                             const float* __restrict__ x,
                                             const float* __restrict__ ampl,
                                             const float* __restrict__ inp,
                                             const float* __restrict__ outv,
                                             const float* __restrict__ pos,
                                             const float* __restrict__ bias,
                                             const float* __restrict__ pdw,
                                             const float* __restrict__ knn) {
    const int bx = blockIdx.x;
    const int tid = threadIdx.x;

    if (bx < 512) {                    // ---- k1: softmax + concat + m ----
        const int row0 = bx * 8;
        const int r    = row0 + (tid >> 5);
        const int lane = tid & 31;

        const float mask = masks[r];
        float v = latent[r*HH + lane] * mask;
        float mx = v;
        #pragma unroll
        for (int off = 16; off > 0; off >>= 1) mx = fmaxf(mx, __shfl_xor(mx, off, 32));
        float e = __expf(v - mx);
        float s = e;
        #pragma unroll
        for (int off = 16; off > 0; off >>= 1) s += __shfl_xor(s, off, 32);
        g_oefb[r*FCC + NFE + lane] = f2bf(e / s * mask);

        if (lane == 0) g_m[r] = mask + x[r*23 + 21] + x[r*23 + 22];

        for (int idx = tid; idx < 8*NFE; idx += 256) {
            int rr = idx / NFE, c = idx - rr*NFE;
            g_oefb[(row0+rr)*FCC + c] = f2bf(x_embeds[(row0+rr)*NFE + c]);
        }
    } else if (bx < 640) {             // ---- k0: zero g_fpad halos ----
        int idx = (bx - 512) * 256 + tid;
        int fzb = idx >> 12;
        int rem = idx & 4095;
        int rowi = rem >> 6;
        int col8 = rem & 63;
        int row = (rowi < 32) ? rowi : (1024 + rowi);
        int4 z = make_int4(0,0,0,0);
        *reinterpret_cast<int4*>(&g_fpad[((size_t)fzb*LPAD + row)*DD + col8*8]) = z;
    } else if (bx < 768) {             // ---- k3c: knn -> bf16 transpose ----
        __shared__ unsigned short tile[64][65];
        int idx2 = bx - 640;
        const int k0 = (idx2 & 7) * 64;
        const int n0 = ((idx2 >> 3) & 7) * 64;
        const int z  = idx2 >> 6;
        const float* __restrict__ src = knn + (size_t)z*FCC*DD;
        #pragma unroll 4
        for (int i = 0; i < 16; ++i) {
            int idx = i*256 + tid;
            int kk = idx >> 6, nn = idx & 63;
            tile[kk][nn] = f2bf(src[(size_t)(k0+kk)*DD + n0+nn]);
        }
        __syncthreads();
        #pragma unroll 4
        for (int i = 0; i < 16; ++i) {
            int idx = i*256 + tid;
            int nn = idx >> 6, kk = idx & 63;
            g_knt[((size_t)z*DD + n0+nn)*FCC + k0+kk] = tile[kk][nn];
        }
    } else if (bx < 800) {             // ---- k3d: small-GEMM B frags ----
        int t = (bx - 768)*256 + tid;
        int lane = t & 63;
        int ks = (t >> 6) & 7;
        int dt = (t >> 9) & 3;
        int o  = t >> 11;
        int l31 = lane & 31, khalf = lane >> 5;
        const float* S = (o == 0) ? ampl + 1*DD*HH :
                         (o == 1) ? ampl + 3*DD*HH :
                         (o == 2) ? ampl + 4*DD*HH : pdw;
        int k0 = dt*128 + ks*16 + khalf*8;
        us8 outw;
        #pragma unroll
        for (int i = 0; i < 8; ++i) outw[i] = f2bf(S[(size_t)(k0+i)*HH + l31]);
        *reinterpret_cast<us8*>(&g_kbs[(size_t)t*8]) = outw;
    } else if (bx < 928) {             // ---- k3b: Gaussian distance table ----
        int idx = (bx - 800) * 256 + tid;
        int h = idx / LL;
        int dist = idx - h*LL;
        float cm = bias[4*HH + h];
        float sig = cm*cm + 1e-4f;
        float dd = (float)dist;
        g_gt[idx] = __expf(-sig * dd * dd);
    } else {                           // ---- k3: conv k in B-frag order ----
        int idx3 = bx - 928;           // 0..1559
        int xi  = idx3 & 7;
        int rem = idx3 >> 3;           // 0..194
        int w   = rem % 65;
        int z   = rem / 65;
        int idx = xi * 256 + tid;      // 0..2047
        const int lane = idx & 63;
        const int ks   = (idx >> 6) & 7;
        const int dt   = idx >> 9;
        const int h    = lane & 31;
        const int d8   = dt*128 + ks*16 + (lane >> 5)*8;

        const float c0 = 0.01f;
        const float p = pos[w];
        int ai, mi, vi;
        if (z == 0)      { ai = 0; mi = 0;  vi = 1; }
        else if (z == 1) { ai = 1; mi = -1; vi = 2; }
        else             { ai = 2; mi = 3;  vi = 4; }

        us8 outw;
        #pragma unroll
        for (int i = 0; i < 8; ++i) {
            int d = d8 + i;
            float a    = ampl[(size_t)ai*DD*HH + d*HH + h];
            float mean = (mi >= 0) ? inp[mi*DD + d] * outv[mi*HH + h] : 0.f;
            float iv   = fabsf(inp[vi*DD + d] * outv[vi*HH + h]) + c0;
            float tt = p - mean;
            outw[i] = f2bf(__expf(-iv * tt * tt) * a);
        }
        *reinterpret_cast<us8*>(&g_kb2[((((size_t)z*WW + w)*4 + dt)*8 + ks)*512 + (size_t)lane*8]) = outw;
    }
}

// ================ K2: cf0/cf1 via MFMA, bf16 in/out ================
// grid (nt=4, mt=64, z=2) = 512 blocks; block 256 = 4 waves; wave = n-quadrant (32 cols)
__global__ __launch_bounds__(256) void k2_mfma() {
    const int nt = blockIdx.x;
    const int mt = blockIdx.y;
    const int z  = blockIdx.z;
    const int t  = threadIdx.x;
    const int wave = t >> 6, lane = t & 63;
    const int l31 = lane & 31, khalf = lane >> 5;
    const int n0 = nt*128 + wave*32;
    const int m_base = mt*64;

    __shared__ __align__(16) unsigned short smem[64*128];  // 16 KB A tile (swizzled)

    f32x16 acc[2];
    #pragma unroll
    for (int mti = 0; mti < 2; ++mti)
        #pragma unroll
        for (int i = 0; i < 16; ++i) acc[mti][i] = 0.f;

    const unsigned short* __restrict__ bptr =
        g_knt + ((size_t)z*DD + n0 + l31)*FCC + khalf*8;

    for (int kc = 0; kc < 4; ++kc) {
        __syncthreads();
        const unsigned short* __restrict__ src = g_oefb + (size_t)m_base*FCC + kc*128;
        #pragma unroll
        for (int c = 0; c < 4; ++c) {
            int q = c*256 + t;
            int row = q >> 4, slot = q & 15;
            int4 v = *reinterpret_cast<const int4*>(src + (size_t)row*FCC + slot*8);
            int off = row*256 + ((slot*16) ^ ((row & 15) << 4));
            *reinterpret_cast<int4*>((char*)smem + off) = v;
        }
        __syncthreads();
        #pragma unroll
        for (int ks = 0; ks < 8; ++ks) {
            bf16x8 bf = *reinterpret_cast<const bf16x8*>(bptr + kc*128 + ks*16);
            int dby = ks*32 + khalf*16;
            #pragma unroll
            for (int mti = 0; mti < 2; ++mti) {
                int r = mti*32 + l31;
                bf16x8 a = *reinterpret_cast<const bf16x8*>(
                    (char*)smem + r*256 + (dby ^ ((r & 15) << 4)));
                acc[mti] = __builtin_amdgcn_mfma_f32_32x32x16_bf16(a, bf, acc[mti], 0, 0, 0);
            }
        }
    }

    #pragma unroll
    for (int mti = 0; mti < 2; ++mti) {
        #pragma unroll
        for (int reg = 0; reg < 16; ++reg) {
            int rowf = (reg & 3) + 8*(reg >> 2) + 4*khalf;
            int m = m_base + mti*32 + rowf;
            int b_ = m >> 10, l_ = m & 1023;
            g_fpad[((size_t)(z*BB + b_)*LPAD + 32 + l_)*DD + n0 + l31] = f2bf(acc[mti][reg]);
        }
    }
}

// ================ KHEAVY: fused k6_vc / k4_mfma / k5_mfma ================
// flat grid 1408: [0,512) k6 (longest role FIRST); [512,1280) k4; [1280,1408) k5.
__global__ __launch_bounds__(256) void kheavy() {
    __shared__ __align__(16) char smem_raw[32768];
    const int bx = blockIdx.x;
    const int t  = threadIdx.x;

    if (bx < 512) {
        // ---------- k6: Toeplitz mask correction (4-way j-ILP) ----------
        float* ml = (float*)smem_raw;  // 4 KB
        const int ib = bx & 127;
        const int b  = bx >> 7;
        for (int j = t; j < LL; j += 256) ml[j] = g_m[b*LL + j];
        __syncthreads();
        const int i = ib * 8 + (t & 7);
        const int h = t >> 3;
        const float* __restrict__ gt = g_gt + (size_t)h * LL;
        float a0 = 0.f, a1 = 0.f, a2 = 0.f, a3 = 0.f;
        #pragma unroll 4
        for (int j = 0; j < 256; ++j) {
            int d0 = i - j;         d0 = d0 < 0 ? -d0 : d0;
            int d1 = i - (j+256);   d1 = d1 < 0 ? -d1 : d1;
            int d2 = i - (j+512);   d2 = d2 < 0 ? -d2 : d2;
            int d3 = i - (j+768);   d3 = d3 < 0 ? -d3 : d3;
            a0 = fmaf(gt[d0], ml[j],       a0);
            a1 = fmaf(gt[d1], ml[j+256],   a1);
            a2 = fmaf(gt[d2], ml[j+512],   a2);
            a3 = fmaf(gt[d3], ml[j+768],   a3);
        }
        g_vsum[(size_t)(b*LL + i)*HH + h] = (a0 + a1) + (a2 + a3);
    } else if (bx < 1280) {
        // ---------- k4: MFMA implicit conv-GEMM, in-block wave reduction ----------
        const int g  = bx - 512;
        const int lt = g & 15;
        const int b  = (g >> 4) & 3;
        const int zdq = g >> 6;
        const int z  = zdq >> 2;
        const int dq = zdq & 3;
        const int fz = (z == 1) ? 1 : 0;
        const int wave = t >> 6, lane = t & 63;
        const int l31 = lane & 31, khalf = lane >> 5;

        const int wbeg = (wave == 0) ? 0 : 17 + (wave - 1)*16;
        const int wend = (wave == 0) ? 17 : wbeg + 16;

        f32x16 acc0, acc1;
        #pragma unroll
        for (int i = 0; i < 16; ++i) { acc0[i] = 0.f; acc1[i] = 0.f; }

        const unsigned short* src =
            g_fpad + ((size_t)(fz*BB + b)*LPAD + lt*64) * DD + dq*128;
        #pragma unroll
        for (int c = 0; c < 8; ++c) {
            int q = c*256 + t;
            int row = q >> 4, slot = q & 15;
            int4 v = *reinterpret_cast<const int4*>(src + (size_t)row*DD + slot*8);
            int off = row*256 + ((slot*16) ^ ((row & 15) << 4));
            *reinterpret_cast<int4*>(smem_raw + off) = v;
        }
        __syncthreads();

        for (int w = wbeg; w < wend; ++w) {
            const unsigned short* kbw =
                g_kb2 + ((((size_t)z*WW + w)*4 + dq)*8)*512;
            const int r0 = l31 + w;
            const int r1 = r0 + 32;
            #pragma unroll
            for (int ks = 0; ks < 8; ++ks) {
                bf16x8 bf = *reinterpret_cast<const bf16x8*>(kbw + ks*512 + lane*8);
                int dby = ks*32 + khalf*16;
                bf16x8 a0 = *reinterpret_cast<const bf16x8*>(
                    smem_raw + r0*256 + (dby ^ ((r0 & 15) << 4)));
                bf16x8 a1 = *reinterpret_cast<const bf16x8*>(
                    smem_raw + r1*256 + (dby ^ ((r1 & 15) << 4)));
                acc0 = __builtin_amdgcn_mfma_f32_32x32x16_bf16(a0, bf, acc0, 0, 0, 0);
                acc1 = __builtin_amdgcn_mfma_f32_32x32x16_bf16(a1, bf, acc1, 0, 0, 0);
            }
        }

        // in-block reduction across the 4 waves (w-quarters)
        __syncthreads();               // all smem A-tile reads done
        float* red = (float*)smem_raw; // 4 waves × 2048 floats = 32 KB
        #pragma unroll
        for (int reg = 0; reg < 16; ++reg) {
            int row = (reg & 3) + 8*(reg >> 2) + 4*khalf;
            red[wave*2048 + row*32 + l31]        = acc0[reg];
            red[wave*2048 + (32 + row)*32 + l31] = acc1[reg];
        }
        __syncthreads();
        float* outp = g_actsp[dq] + (size_t)z*BLH + ((size_t)b*LL + lt*64)*HH;
        #pragma unroll
        for (int j = 0; j < 8; ++j) {
            int i = j*256 + t;
            float sum = red[i] + red[2048 + i] + red[4096 + i] + red[6144 + i];
            outp[i] = sum;
        }
    } else {
        // ---------- k5: small GEMMs via MFMA (M=4096, N=32, K=512) ----------
        const int g = bx - 1280;
        const int mt = g & 31;
        const int o  = g >> 5;
        const int wave = t >> 6, lane = t & 63;
        const int l31 = lane & 31, khalf = lane >> 5;

        const unsigned short* src;
        if (o == 3) {
            src = g_oefb + (size_t)mt*128*FCC;
        } else {
            const int fz = (o == 1) ? 0 : 1;
            const int m0 = mt*128;
            const int b_ = m0 >> 10, l0 = m0 & 1023;
            src = g_fpad + ((size_t)(fz*BB + b_)*LPAD + 32 + l0)*DD;
        }

        f32x16 acc;
        #pragma unroll
        for (int i = 0; i < 16; ++i) acc[i] = 0.f;

        for (int kc = 0; kc < 4; ++kc) {
            __syncthreads();
            const unsigned short* s2 = src + kc*128;
            #pragma unroll
            for (int c = 0; c < 8; ++c) {
                int q = c*256 + t;
                int row = q >> 4, slot = q & 15;
                int4 v = *reinterpret_cast<const int4*>(s2 + (size_t)row*512 + slot*8);
                int off = row*256 + ((slot*16) ^ ((row & 15) << 4));
                *reinterpret_cast<int4*>(smem_raw + off) = v;
            }
            __syncthreads();
            #pragma unroll
            for (int ks = 0; ks < 8; ++ks) {
                bf16x8 bf = *reinterpret_cast<const bf16x8*>(
                    &g_kbs[((((size_t)o*4 + kc)*8 + ks)*64 + lane)*8]);
                int dby = ks*32 + khalf*16;
                int r = wave*32 + l31;
                bf16x8 a = *reinterpret_cast<const bf16x8*>(
                    smem_raw + r*256 + (dby ^ ((r & 15) << 4)));
                acc = __builtin_amdgcn_mfma_f32_32x32x16_bf16(a, bf, acc, 0, 0, 0);
            }
        }

        float* outp = g_small + (size_t)o*BLH + ((size_t)mt*128 + wave*32)*HH;
        #pragma unroll
        for (int reg = 0; reg < 16; ++reg) {
            int row = (reg & 3) + 8*(reg >> 2) + 4*khalf;
            outp[(size_t)row*HH + l31] = acc[reg];
        }
    }
}

// ================ K7: final combine (sums the 4 dq partial slots) ================
__global__ __launch_bounds__(256) void k7_final(const float* __restrict__ masks,
                                                const float* __restrict__ bias,
                                                float* __restrict__ out) {
    int idx = blockIdx.x * 256 + threadIdx.x;
    int r = idx >> 5, h = idx & 31;
    float a0 = 0.f, a1 = 0.f, a2 = 0.f;
    #pragma unroll
    for (int s = 0; s < 4; ++s) {
        a0 += g_actsp[s][idx];
        a1 += g_actsp[s][BLH + idx];
        a2 += g_actsp[s][2*BLH + idx];
    }
    float rdf = (a0 + bias[0*HH + h]) * a1
              + a2 * (g_small[idx] + bias[2*HH + h])
              + (g_small[BLH + idx] + bias[1*HH + h]) * g_small[2*BLH + idx];
    float pp = g_small[3*BLH + idx] + bias[3*HH + h];
    float vc = g_m[r] * g_vsum[idx];
    out[idx] = vc * pp * rdf * masks[r];
}

extern "C" void kernel_launch(void* const* d_in, const int* in_sizes, int n_in,
                              void* d_out, int out_size, void* d_ws, size_t ws_size,
                              hipStream_t stream) {
    (void)in_sizes; (void)n_in; (void)d_ws; (void)ws_size; (void)out_size;
    const float* x_embeds = (const float*)d_in[0];
    const float* latent   = (const float*)d_in[1];
    const float* masks    = (const float*)d_in[2];
    const float* pos      = (const float*)d_in[3];
    const float* x        = (const float*)d_in[4];
    const float* ampl     = (const float*)d_in[5];
    const float* inp      = (const float*)d_in[6];
    const float* outv     = (const float*)d_in[7];
    const float* bias     = (const float*)d_in[8];
    const float* pdw      = (const float*)d_in[9];
    const float* knn      = (const float*)d_in[10];
    float* out = (float*)d_out;

    hipLaunchKernelGGL(kprep, dim3(2488), dim3(256), 0, stream,
                       x_embeds, latent, masks, x, ampl, inp, outv, pos, bias, pdw, knn);
    hipLaunchKernelGGL(k2_mfma, dim3(4, 64, 2), dim3(256), 0, stream);
    hipLaunchKernelGGL(kheavy, dim3(1408), dim3(256), 0, stream);
    hipLaunchKernelGGL(k7_final, dim3(BLH/256), dim3(256), 0, stream, masks, bias, out);
}